// Round 16
// baseline (2681.124 us; speedup 1.0000x reference)
//
#include <hip/hip_runtime.h>
#include <math.h>
#include <cmath>

// Problem constants
#define BB 8
#define CC 2048
#define DD 64
#define LL 3
#define HH 4
#define DHH 16
#define KPAD 40   // halves per LDS row: 32 keys + 8 pad (80B = 16B-aligned)
#define GCLAMP 4.25f

typedef _Float16 half8 __attribute__((ext_vector_type(8)));
typedef _Float16 h2    __attribute__((ext_vector_type(2)));
typedef float f32x4 __attribute__((ext_vector_type(4)));

#if defined(__has_builtin)
#if __has_builtin(__builtin_amdgcn_exp2f)
#define EXP2F(x) __builtin_amdgcn_exp2f(x)
#else
#define EXP2F(x) __expf((x) * 0.693147180559945f)
#endif
#else
#define EXP2F(x) __expf((x) * 0.693147180559945f)
#endif

// ---------------- exact GELU via A&S 7.1.26 erf (residual-path kernels) ----------------
__device__ __forceinline__ float gelu_f(float x) {
    float z  = 0.70710678118654752f * x;
    float az = fabsf(z);
    float t  = __builtin_amdgcn_rcpf(fmaf(0.3275911f, az, 1.0f));
    float p  = t * fmaf(t, fmaf(t, fmaf(t, fmaf(t, 1.061405429f, -1.453152027f),
                                        1.421413741f), -0.284496736f), 0.254829592f);
    float e  = __expf(-z * z);
    float r  = p * e;                                // erfc(|z|)
    float phi = (x >= 0.0f) ? fmaf(-0.5f, r, 1.0f) : 0.5f * r;
    return x * phi;
}

__device__ __forceinline__ float wave_sum64(float v) {
    #pragma unroll
    for (int off = 32; off; off >>= 1) v += __shfl_xor(v, off, 64);
    return v;
}

// ---------------- fp16 packed erf-GELU score pair ----------------
// For 2 hidden values x0,x1: s += w_a*gelu(x0) + w_b*gelu(x1), with w already
// carrying 0.5 (gelu = 0.5*x*(1+E)). E(t)=erf(t/sqrt2) ~ t*P(v), v=t^2/GCLAMP^2,
// Horner in half2 (v_pk_*_f16). w*x stays f32 so the linear part is exact.
__device__ __forceinline__ float score_pair(float x0, float x1, float wa, float wb, float s,
                                            h2 C0, h2 C1, h2 C2, h2 C3, h2 C4,
                                            h2 IVU, h2 LO, h2 HI) {
    h2 t = __builtin_bit_cast(h2, __builtin_amdgcn_cvt_pkrtz(x0, x1));
    t = __builtin_elementwise_min(__builtin_elementwise_max(t, LO), HI);
    h2 u = t * t;
    h2 v = u * IVU;
    h2 P = __builtin_elementwise_fma(C4, v, C3);
    P = __builtin_elementwise_fma(P, v, C2);
    P = __builtin_elementwise_fma(P, v, C1);
    P = __builtin_elementwise_fma(P, v, C0);
    h2 E = t * P;
    float m0 = wa * x0, m1 = wb * x1;
    s = s + m0;
    s = fmaf(m0, (float)E.x, s);
    s = s + m1;
    s = fmaf(m1, (float)E.y, s);
    return s;
}

// ---------------- host: deg-4 LSQ fit of erf(t/sqrt2) ~ t*P(v), v=t^2/umax ----------------
static void fit_gelu_poly(float cf[5]) {
    const int NS = 512;
    const int M = 5;
    const double umax = (double)GCLAMP * (double)GCLAMP;
    double AtA[5][5], Atb[5];
    for (int i = 0; i < M; ++i) { Atb[i] = 0.0; for (int j = 0; j < M; ++j) AtA[i][j] = 0.0; }
    for (int k = 0; k <= NS; ++k) {
        double u = umax * 0.5 * (1.0 - cos(3.14159265358979323846 * (double)k / NS));
        double t = sqrt(u);
        double g = erf(t * 0.7071067811865476);
        double v = u / umax;
        double phi[5];
        double p = t;
        for (int j = 0; j < M; ++j) { phi[j] = p; p *= v; }
        for (int i = 0; i < M; ++i) {
            Atb[i] += phi[i] * g;
            for (int j = 0; j < M; ++j) AtA[i][j] += phi[i] * phi[j];
        }
    }
    for (int col = 0; col < M; ++col) {              // GE w/ partial pivoting
        int piv = col;
        for (int r = col + 1; r < M; ++r)
            if (fabs(AtA[r][col]) > fabs(AtA[piv][col])) piv = r;
        if (piv != col) {
            for (int j = 0; j < M; ++j) { double tm = AtA[col][j]; AtA[col][j] = AtA[piv][j]; AtA[piv][j] = tm; }
            double tb = Atb[col]; Atb[col] = Atb[piv]; Atb[piv] = tb;
        }
        double d = AtA[col][col];
        for (int r = col + 1; r < M; ++r) {
            double f = AtA[r][col] / d;
            for (int j = col; j < M; ++j) AtA[r][j] -= f * AtA[col][j];
            Atb[r] -= f * Atb[col];
        }
    }
    double c[5];
    for (int i = M - 1; i >= 0; --i) {
        double s = Atb[i];
        for (int j = i + 1; j < M; ++j) s -= AtA[i][j] * c[j];
        c[i] = s / AtA[i][i];
    }
    for (int j = 0; j < M; ++j) cf[j] = (float)c[j];  // v-basis, O(0.01..0.8): fp16-safe
}

// ---------------- binding encoder ----------------
__global__ __launch_bounds__(256) void k_binding(const float* __restrict__ x,
                                                 const float* __restrict__ role,
                                                 const float* __restrict__ fw,
                                                 float* __restrict__ h) {
    int idx = blockIdx.x * 256 + threadIdx.x;        // B*C*D = 1048576
    int d  = idx & 63;
    int bc = idx >> 6;
    float xl = log1pf(fmaxf(x[bc], 0.0f));
    float f  = gelu_f(xl * fw[d]);
    h[idx] = role[(bc & (CC - 1)) * DD + d] * f;
}

// ---------------- QKV projection + Aq (=qp+b1) precompute ----------------
__global__ __launch_bounds__(256) void k_qkv(const float* __restrict__ h,
                                             const float* __restrict__ qw, const float* __restrict__ qb,
                                             const float* __restrict__ kw, const float* __restrict__ kb,
                                             const float* __restrict__ vw, const float* __restrict__ vb,
                                             const float* __restrict__ w1, const float* __restrict__ b1,
                                             float* __restrict__ Q, float* __restrict__ K,
                                             float* __restrict__ V, float* __restrict__ A) {
    __shared__ __attribute__((aligned(16))) float hrow[4][64];
    __shared__ float qrow[4][64];
    int r  = threadIdx.x >> 6;
    int j  = threadIdx.x & 63;
    int bc = blockIdx.x * 4 + r;                     // 0..16383
    hrow[r][j] = h[(size_t)bc * 64 + j];
    __syncthreads();
    float aq = qb[j], ak = kb[j], av = vb[j];
    const float4* hr4 = (const float4*)hrow[r];
    const float4* qw4 = (const float4*)(qw + j * 64);
    const float4* kw4 = (const float4*)(kw + j * 64);
    const float4* vw4 = (const float4*)(vw + j * 64);
    #pragma unroll
    for (int i = 0; i < 16; ++i) {
        float4 hv = hr4[i];
        float4 a = qw4[i], b = kw4[i], c = vw4[i];
        aq = fmaf(hv.x, a.x, fmaf(hv.y, a.y, fmaf(hv.z, a.z, fmaf(hv.w, a.w, aq))));
        ak = fmaf(hv.x, b.x, fmaf(hv.y, b.y, fmaf(hv.z, b.z, fmaf(hv.w, b.w, ak))));
        av = fmaf(hv.x, c.x, fmaf(hv.y, c.y, fmaf(hv.z, c.z, fmaf(hv.w, c.w, av))));
    }
    int head = j >> 4, dh = j & 15;
    int b = bc >> 11, c = bc & (CC - 1);
    size_t o = ((size_t)(b * HH + head) * CC + c) * DHH + dh;
    Q[o] = aq; K[o] = ak; V[o] = av;
    qrow[r][j] = aq;
    __syncthreads();
    float aA = b1[dh];
    #pragma unroll
    for (int i = 0; i < 16; ++i)
        aA = fmaf(qrow[r][head * 16 + i], w1[dh * 48 + i], aA);
    A[o] = aA;
}

// ---------------- MFMA attention with MLP scores (8 q/wave, spill-free at 6 waves) ----------------
// grid: qt(64, 32 queries each) x bh(32) = 2048 blocks, 4 waves/block, 8 q/wave.
// Round-15 proved the dieted kernel (no prefetch, serialized D0/D1) has ~46 VGPR
// overhead + bq. bq[8]=32 -> ~78 live <= 84 cap of (256,6): 8 q/wave now fits
// spill-free (round 12 couldn't: prefetch regs pushed it to ~90). Tile-shared costs
// (staging, 2 EV-MFMAs, barriers, bK reads, El zeroing) amortize over 2x queries.
__global__ __launch_bounds__(256, 6) void k_attn(const float* __restrict__ Q, const float* __restrict__ K,
                                                 const float* __restrict__ V, const float* __restrict__ A,
                                                 const float* __restrict__ w1g, const float* __restrict__ w2g,
                                                 float* __restrict__ AT,
                                                 float c0, float c1, float c2, float c3, float c4) {
    __shared__ __attribute__((aligned(16))) _Float16 Kl[32 * KPAD];   // [key][i0..15,16=1,17..=0]
    __shared__ __attribute__((aligned(16))) _Float16 Vt[16 * KPAD];   // [d][key]
    __shared__ __attribute__((aligned(16))) _Float16 El[4][16 * KPAD];// per wave [q][key]

    int tid  = threadIdx.x;
    int lane = tid & 63;
    int w    = tid >> 6;
    int quad = lane >> 4;
    int l15  = lane & 15;
    int qt = blockIdx.x & 63;
    int bh = blockIdx.x >> 6;
    size_t base = (size_t)bh * (CC * DHH);
    int qbase = qt * 32 + w * 8;

    // one-time: Kl const region ([16]=1, rest 0) + zero ALL of El (rows 8..15 stay 0)
    for (int idx = tid; idx < 32 * 24; idx += 256) {
        int row = idx / 24, off = 16 + idx % 24;
        Kl[row * KPAD + off] = (off == 16) ? (_Float16)1.0f : (_Float16)0.0f;
    }
    {
        _Float16* Elf = &El[0][0];
        for (int idx = tid; idx < 4 * 16 * KPAD; idx += 256) Elf[idx] = (_Float16)0.0f;
    }

    // gelu poly constants (half2)
    h2 C0 = {(_Float16)c0, (_Float16)c0};
    h2 C1 = {(_Float16)c1, (_Float16)c1};
    h2 C2 = {(_Float16)c2, (_Float16)c2};
    h2 C3 = {(_Float16)c3, (_Float16)c3};
    h2 C4 = {(_Float16)c4, (_Float16)c4};
    const float ivu_f = 1.0f / (GCLAMP * GCLAMP);
    h2 IVU = {(_Float16)ivu_f, (_Float16)ivu_f};
    h2 LO = {(_Float16)(-GCLAMP), (_Float16)(-GCLAMP)};
    h2 HI = {(_Float16)GCLAMP, (_Float16)GCLAMP};

    // per-lane w2 for rows j = quad*4+r; fold 1/sqrt(16)*log2(e)*0.5 (gelu half)
    float w2h[4];
    #pragma unroll
    for (int r = 0; r < 4; ++r) w2h[r] = w2g[quad * 4 + r] * (0.25f * 1.44269504f * 0.5f);

    bool sel_hi = (lane & 16) != 0;                  // quads 1,3 -> sub1 value at store

    // Bq A-frags: m=j=lane&15, kdim=i=quad*8+jj. quads0,1: W1qk[j][i]*q[i]+W1k[j][i];
    // quad2 jj=0: Aq[j]; else 0. 8 frags (32 regs) live across the K loop.
    half8 bq[8];
    {
        int j = l15;
        #pragma unroll
        for (int q = 0; q < 8; ++q) {
            const float* qv = Q + base + (size_t)(qbase + q) * 16;
            float aqv = A[base + (size_t)(qbase + q) * 16 + j];
            half8 v;
            #pragma unroll
            for (int jj = 0; jj < 8; ++jj) {
                float val;
                if (quad < 2) {
                    int i = quad * 8 + jj;
                    val = fmaf(w1g[j * 48 + 32 + i], qv[i], w1g[j * 48 + 16 + i]);
                } else if (quad == 2 && jj == 0) {
                    val = aqv;
                } else {
                    val = 0.0f;
                }
                v[jj] = (_Float16)val;
            }
            bq[q] = v;
        }
    }

    half8 ones;
    #pragma unroll
    for (int jj = 0; jj < 8; ++jj) ones[jj] = (_Float16)1.0f;
    f32x4 Oc = {0.f, 0.f, 0.f, 0.f};
    f32x4 Dn = {0.f, 0.f, 0.f, 0.f};
    f32x4 zc = {0.f, 0.f, 0.f, 0.f};

    _Float16* Ew = El[w];

    // staging index map (fixed per thread)
    int skey = tid >> 3, sip = (tid & 7) * 2;        // K: thread -> (key, elem-pair)
    int vk0 = tid >> 4,          vd0 = tid & 15;     // V elem 0
    int vk1 = (tid + 256) >> 4,  vd1 = tid & 15;     // V elem 1

    #pragma unroll 1
    for (int t0 = 0; t0 < CC; t0 += 32) {
        __syncthreads();                              // prior tile's LDS readers done
        {   // stage K/V directly (short live ranges; no cross-iteration prefetch regs)
            float2 kv = *(const float2*)(K + base + (size_t)(t0 + skey) * 16 + sip);
            Kl[skey * KPAD + sip]     = (_Float16)kv.x;
            Kl[skey * KPAD + sip + 1] = (_Float16)kv.y;
            Vt[vd0 * KPAD + vk0] = (_Float16)V[base + (size_t)(t0 + vk0) * 16 + vd0];
            Vt[vd1 * KPAD + vk1] = (_Float16)V[base + (size_t)(t0 + vk1) * 16 + vd1];
        }
        __syncthreads();                              // staging visible to all waves

        half8 bK0 = *(const half8*)&Kl[l15 * KPAD + quad * 8];
        half8 bK1 = *(const half8*)&Kl[(16 + l15) * KPAD + quad * 8];

        #pragma unroll
        for (int q = 0; q < 8; ++q) {
            float s0 = 0.0f, s1 = 0.0f;
            {   // sub0: MFMA + score chain (D0 dies before D1 is produced)
                f32x4 D0 = __builtin_amdgcn_mfma_f32_16x16x32_f16(bq[q], bK0, zc, 0, 0, 0);
                s0 = score_pair(D0[0], D0[1], w2h[0], w2h[1], s0, C0, C1, C2, C3, C4, IVU, LO, HI);
                s0 = score_pair(D0[2], D0[3], w2h[2], w2h[3], s0, C0, C1, C2, C3, C4, IVU, LO, HI);
            }
            {   // sub1
                f32x4 D1 = __builtin_amdgcn_mfma_f32_16x16x32_f16(bq[q], bK1, zc, 0, 0, 0);
                s1 = score_pair(D1[0], D1[1], w2h[0], w2h[1], s1, C0, C1, C2, C3, C4, IVU, LO, HI);
                s1 = score_pair(D1[2], D1[3], w2h[2], w2h[3], s1, C0, C1, C2, C3, C4, IVU, LO, HI);
            }
            s0 += __shfl_xor(s0, 16, 64);
            s0 += __shfl_xor(s0, 32, 64);
            s1 += __shfl_xor(s1, 16, 64);
            s1 += __shfl_xor(s1, 32, 64);
            float uu = sel_hi ? s1 : s0;              // lanes 16..31 carry sub1
            float e = EXP2F(uu);                      // base-2 softmax (log2e folded in w2h)
            if (lane < 32) Ew[q * KPAD + lane] = (_Float16)e;
        }
        // E·V numerator + E·ones denominator (A rows 8..15 are zero -> inert)
        half8 aE = *(const half8*)&Ew[l15 * KPAD + quad * 8];
        half8 bV = *(const half8*)&Vt[l15 * KPAD + quad * 8];
        Oc = __builtin_amdgcn_mfma_f32_16x16x32_f16(aE, bV, Oc, 0, 0, 0);
        Dn = __builtin_amdgcn_mfma_f32_16x16x32_f16(aE, ones, Dn, 0, 0, 0);
    }

    // D layout: row(q)=quad*4+r, col(d)=lane&15; only rows 0..7 (quad<2) are real q's
    int b = bh >> 2, hh = bh & 3;
    if (quad < 2) {
        #pragma unroll
        for (int r = 0; r < 4; ++r) {
            int c = qbase + quad * 4 + r;
            AT[((size_t)(b * CC + c)) * DD + hh * 16 + l15] = Oc[r] / Dn[r];
        }
    }
}

// ---------------- fused post-attention: oproj + LN1 + FFN + LN2 (4 rows/block) ----------------
// Weights loaded once per thread and reused across 4 rows (4x less L2 traffic);
// each wave owns one row for the LN phases (no idle waves).
__global__ __launch_bounds__(256) void k_post(const float* __restrict__ AT,
                                              const float* __restrict__ ow, const float* __restrict__ ob,
                                              const float* __restrict__ g1, const float* __restrict__ be1,
                                              const float* __restrict__ f1w, const float* __restrict__ f1b,
                                              const float* __restrict__ f2w, const float* __restrict__ f2b,
                                              const float* __restrict__ g2, const float* __restrict__ be2,
                                              float* __restrict__ h) {
    int bc0 = blockIdx.x * 4;
    int t  = threadIdx.x;
    int j = t & 63, wv = t >> 6;
    __shared__ __attribute__((aligned(16))) float ar[4][64];
    __shared__ __attribute__((aligned(16))) float hln[4][64];
    __shared__ __attribute__((aligned(16))) float u[4][256];
    __shared__ float parts[4][4][64];                // [row][chunk][j]
    ar[wv][j] = AT[(size_t)(bc0 + wv) * 64 + j];
    __syncthreads();
    {   // out-proj partials: thread (wv=chunk, j=out) for all 4 rows
        float p0 = 0.f, p1 = 0.f, p2 = 0.f, p3 = 0.f;
        const float4* w4 = (const float4*)(ow + j * 64 + wv * 16);
        const float4* a0 = (const float4*)(ar[0] + wv * 16);
        const float4* a1 = (const float4*)(ar[1] + wv * 16);
        const float4* a2 = (const float4*)(ar[2] + wv * 16);
        const float4* a3 = (const float4*)(ar[3] + wv * 16);
        #pragma unroll
        for (int i = 0; i < 4; ++i) {
            float4 wvv = w4[i];
            float4 x0 = a0[i], x1 = a1[i], x2 = a2[i], x3 = a3[i];
            p0 = fmaf(x0.x, wvv.x, fmaf(x0.y, wvv.y, fmaf(x0.z, wvv.z, fmaf(x0.w, wvv.w, p0))));
            p1 = fmaf(x1.x, wvv.x, fmaf(x1.y, wvv.y, fmaf(x1.z, wvv.z, fmaf(x1.w, wvv.w, p1))));
            p2 = fmaf(x2.x, wvv.x, fmaf(x2.y, wvv.y, fmaf(x2.z, wvv.z, fmaf(x2.w, wvv.w, p2))));
            p3 = fmaf(x3.x, wvv.x, fmaf(x3.y, wvv.y, fmaf(x3.z, wvv.z, fmaf(x3.w, wvv.w, p3))));
        }
        parts[0][wv][j] = p0; parts[1][wv][j] = p1; parts[2][wv][j] = p2; parts[3][wv][j] = p3;
    }
    __syncthreads();
    {   // LN1: wave wv handles row wv
        float o = ob[j] + parts[wv][0][j] + parts[wv][1][j] + parts[wv][2][j] + parts[wv][3][j];
        float x = h[(size_t)(bc0 + wv) * 64 + j] + o;
        float m  = wave_sum64(x) * (1.0f / 64.0f);
        float dv = x - m;
        float vv = wave_sum64(dv * dv) * (1.0f / 64.0f);
        float r  = __builtin_amdgcn_rsqf(vv + 1e-5f);
        hln[wv][j] = fmaf(dv * r, g1[j], be1[j]);
    }
    __syncthreads();
    {   // FFN1: thread t computes hidden unit t for all 4 rows (weights loaded once)
        float b = f1b[t];
        float a0 = b, a1 = b, a2 = b, a3 = b;
        const float4* w4 = (const float4*)(f1w + t * 64);
        const float4* h0 = (const float4*)hln[0];
        const float4* h1 = (const float4*)hln[1];
        const float4* h2p = (const float4*)hln[2];
        const float4* h3 = (const float4*)hln[3];
        #pragma unroll
        for (int i = 0; i < 16; ++i) {
            float4 wvv = w4[i];
            float4 x0 = h0[i], x1 = h1[i], x2 = h2p[i], x3 = h3[i];
            a0 = fmaf(x0.x, wvv.x, fmaf(x0.y, wvv.y, fmaf(x0.z, wvv.z, fmaf(x0.w, wvv.w, a0))));
            a1 = fmaf(x1.x, wvv.x, fmaf(x1.y, wvv.y, fmaf(x1.z, wvv.z, fmaf(x1.w, wvv.w, a1))));
            a2 = fmaf(x2.x, wvv.x, fmaf(x2.y, wvv.y, fmaf(x2.z, wvv.z, fmaf(x2.w, wvv.w, a2))));
            a3 = fmaf(x3.x, wvv.x, fmaf(x3.y, wvv.y, fmaf(x3.z, wvv.z, fmaf(x3.w, wvv.w, a3))));
        }
        u[0][t] = gelu_f(a0); u[1][t] = gelu_f(a1); u[2][t] = gelu_f(a2); u[3][t] = gelu_f(a3);
    }
    __syncthreads();
    {   // FFN2 partials
        float p0 = 0.f, p1 = 0.f, p2 = 0.f, p3 = 0.f;
        const float4* w4 = (const float4*)(f2w + j * 256 + wv * 64);
        const float4* u0 = (const float4*)(u[0] + wv * 64);
        const float4* u1 = (const float4*)(u[1] + wv * 64);
        const float4* u2 = (const float4*)(u[2] + wv * 64);
        const float4* u3 = (const float4*)(u[3] + wv * 64);
        #pragma unroll
        for (int i = 0; i < 16; ++i) {
            float4 wvv = w4[i];
            float4 x0 = u0[i], x1 = u1[i], x2 = u2[i], x3 = u3[i];
            p0 = fmaf(x0.x, wvv.x, fmaf(x0.y, wvv.y, fmaf(x0.z, wvv.z, fmaf(x0.w, wvv.w, p0))));
            p1 = fmaf(x1.x, wvv.x, fmaf(x1.y, wvv.y, fmaf(x1.z, wvv.z, fmaf(x1.w, wvv.w, p1))));
            p2 = fmaf(x2.x, wvv.x, fmaf(x2.y, wvv.y, fmaf(x2.z, wvv.z, fmaf(x2.w, wvv.w, p2))));
            p3 = fmaf(x3.x, wvv.x, fmaf(x3.y, wvv.y, fmaf(x3.z, wvv.z, fmaf(x3.w, wvv.w, p3))));
        }
        parts[0][wv][j] = p0; parts[1][wv][j] = p1; parts[2][wv][j] = p2; parts[3][wv][j] = p3;
    }
    __syncthreads();
    {   // LN2: wave wv handles row wv
        float o = f2b[j] + parts[wv][0][j] + parts[wv][1][j] + parts[wv][2][j] + parts[wv][3][j];
        float x = hln[wv][j] + o;
        float m  = wave_sum64(x) * (1.0f / 64.0f);
        float dv = x - m;
        float vv = wave_sum64(dv * dv) * (1.0f / 64.0f);
        float r  = __builtin_amdgcn_rsqf(vv + 1e-5f);
        h[(size_t)(bc0 + wv) * 64 + j] = fmaf(dv * r, g2[j], be2[j]);
    }
}

// ---------------- task-query readout ----------------
__global__ __launch_bounds__(256) void k_readout(const float* __restrict__ h,
                                                 const float* __restrict__ tq,
                                                 const float* __restrict__ hw, const float* __restrict__ hb,
                                                 float* __restrict__ out) {
    int b = blockIdx.x;
    int t = threadIdx.x;
    __shared__ float ebuf[2048];
    __shared__ float tqs[64];
    __shared__ float sred[256];
    __shared__ float red[4][64];
    if (t < 64) tqs[t] = tq[t];
    __syncthreads();
    float ss = 0.0f;
    for (int c = t; c < CC; c += 256) {
        const float* hrow = h + ((size_t)b * CC + c) * 64;
        float s = 0.0f;
        #pragma unroll
        for (int d = 0; d < 64; ++d) s = fmaf(hrow[d], tqs[d], s);
        float e = __expf(s * 0.125f);                 // scores ~ +-0.1: max-free safe
        ebuf[c] = e; ss += e;
    }
    sred[t] = ss;
    __syncthreads();
    for (int o = 128; o; o >>= 1) {
        if (t < o) sred[t] += sred[t + o];
        __syncthreads();
    }
    float inv = 1.0f / sred[0];
    int d = t & 63, ch = t >> 6;
    float p = 0.0f;
    for (int c = ch * 512; c < ch * 512 + 512; ++c)
        p = fmaf(ebuf[c], h[((size_t)b * CC + c) * 64 + d], p);
    red[ch][d] = p;
    __syncthreads();
    if (t < 64) red[0][t] = (red[0][t] + red[1][t] + red[2][t] + red[3][t]) * inv;
    __syncthreads();
    if (t < 10) {
        float o = hb[t];
        #pragma unroll
        for (int d2 = 0; d2 < 64; ++d2) o = fmaf(red[0][d2], hw[t * 64 + d2], o);
        out[b * 10 + t] = o;
    }
}

extern "C" void kernel_launch(void* const* d_in, const int* in_sizes, int n_in,
                              void* d_out, int out_size, void* d_ws, size_t ws_size,
                              hipStream_t stream) {
    (void)in_sizes; (void)n_in; (void)out_size; (void)ws_size;
    const float* x    = (const float*)d_in[0];
    const float* role = (const float*)d_in[1];
    const float* fw   = (const float*)d_in[2];
    const float* qw   = (const float*)d_in[3];
    const float* qb   = (const float*)d_in[4];
    const float* kw   = (const float*)d_in[5];
    const float* kb   = (const float*)d_in[6];
    const float* vw   = (const float*)d_in[7];
    const float* vb   = (const float*)d_in[8];
    const float* w1   = (const float*)d_in[9];
    const float* b1   = (const float*)d_in[10];
    const float* w2   = (const float*)d_in[11];
    // d_in[12] = b2: softmax-shift-invariant, dropped
    const float* ow   = (const float*)d_in[13];
    const float* ob   = (const float*)d_in[14];
    const float* g1   = (const float*)d_in[15];
    const float* be1  = (const float*)d_in[16];
    const float* f1w  = (const float*)d_in[17];
    const float* f1b  = (const float*)d_in[18];
    const float* f2w  = (const float*)d_in[19];
    const float* f2b  = (const float*)d_in[20];
    const float* g2   = (const float*)d_in[21];
    const float* be2  = (const float*)d_in[22];
    const float* tq   = (const float*)d_in[23];
    const float* hw   = (const float*)d_in[24];
    const float* hb   = (const float*)d_in[25];

    float cf[5];
    fit_gelu_poly(cf);                               // deterministic per call (~us, host-only)

    float* ws   = (float*)d_ws;
    const size_t M = 1048576;                        // B*C*D
    float* H    = ws;
    float* Q    = ws + 1 * M;
    float* K    = ws + 2 * M;
    float* V    = ws + 3 * M;
    float* Abuf = ws + 4 * M;
    float* AT   = ws + 5 * M;

    k_binding<<<4096, 256, 0, stream>>>(x, role, fw, H);
    for (int l = 0; l < LL; ++l) {
        k_qkv<<<4096, 256, 0, stream>>>(H, qw + l * 4096, qb + l * 64, kw + l * 4096, kb + l * 64,
                                        vw + l * 4096, vb + l * 64, w1 + l * 768, b1 + l * 16,
                                        Q, K, V, Abuf);
        k_attn<<<2048, 256, 0, stream>>>(Q, K, V, Abuf, w1 + l * 768, w2 + l * 16, AT,
                                         cf[0], cf[1], cf[2], cf[3], cf[4]);
        k_post<<<4096, 256, 0, stream>>>(AT, ow + l * 4096, ob + l * 64, g1 + l * 64, be1 + l * 64,
                                         f1w + l * 16384, f1b + l * 256, f2w + l * 16384,
                                         f2b + l * 64, g2 + l * 64, be2 + l * 64, H);
    }
    k_readout<<<8, 256, 0, stream>>>(H, tq, hw, hb, (float*)d_out);
}

// Round 17
// 2492.624 us; speedup vs baseline: 1.0756x; 1.0756x over previous
//
#include <hip/hip_runtime.h>
#include <math.h>
#include <cmath>

// Problem constants
#define BB 8
#define CC 2048
#define DD 64
#define LL 3
#define HH 4
#define DHH 16
#define KPAD 40   // halves per LDS row: 32 keys + 8 pad (80B = 16B-aligned)
#define GCLAMP 4.25f

typedef _Float16 half8 __attribute__((ext_vector_type(8)));
typedef _Float16 h2    __attribute__((ext_vector_type(2)));
typedef float f32x4 __attribute__((ext_vector_type(4)));

#if defined(__has_builtin)
#if __has_builtin(__builtin_amdgcn_exp2f)
#define EXP2F(x) __builtin_amdgcn_exp2f(x)
#else
#define EXP2F(x) __expf((x) * 0.693147180559945f)
#endif
#else
#define EXP2F(x) __expf((x) * 0.693147180559945f)
#endif

// ---------------- exact GELU via A&S 7.1.26 erf (residual-path kernels) ----------------
__device__ __forceinline__ float gelu_f(float x) {
    float z  = 0.70710678118654752f * x;
    float az = fabsf(z);
    float t  = __builtin_amdgcn_rcpf(fmaf(0.3275911f, az, 1.0f));
    float p  = t * fmaf(t, fmaf(t, fmaf(t, fmaf(t, 1.061405429f, -1.453152027f),
                                        1.421413741f), -0.284496736f), 0.254829592f);
    float e  = __expf(-z * z);
    float r  = p * e;                                // erfc(|z|)
    float phi = (x >= 0.0f) ? fmaf(-0.5f, r, 1.0f) : 0.5f * r;
    return x * phi;
}

__device__ __forceinline__ float wave_sum64(float v) {
    #pragma unroll
    for (int off = 32; off; off >>= 1) v += __shfl_xor(v, off, 64);
    return v;
}

// ---------------- fully-fp16 packed erf-GELU score for one f32x4 sub-tile ----------------
// sum_j w_j * gelu(x_j) over 4 values, all-packed fp16: gelu = 0.5x(1+E),
// E(t)=erf(t/sqrt2) ~ t*P(v), v=t^2/GCLAMP^2. 0.5 and softmax log2e folded in W.
// m = W*t_raw (fp16; |terms| ~0.02, err ~5e-4 rel -> absmax ~1e-4, threshold 1.3e-3).
__device__ __forceinline__ float score_sub(f32x4 D, h2 WA, h2 WB,
                                           h2 C0, h2 C1, h2 C2, h2 C3, h2 C4,
                                           h2 IVU, h2 LO, h2 HI) {
    h2 sh = {(_Float16)0.0f, (_Float16)0.0f};
    {
        h2 tr = __builtin_bit_cast(h2, __builtin_amdgcn_cvt_pkrtz(D[0], D[1]));
        h2 t  = __builtin_elementwise_min(__builtin_elementwise_max(tr, LO), HI);
        h2 u = t * t;
        h2 v = u * IVU;
        h2 P = __builtin_elementwise_fma(C4, v, C3);
        P = __builtin_elementwise_fma(P, v, C2);
        P = __builtin_elementwise_fma(P, v, C1);
        P = __builtin_elementwise_fma(P, v, C0);
        h2 E = t * P;
        h2 m = WA * tr;
        sh = __builtin_elementwise_fma(m, E, sh + m);
    }
    {
        h2 tr = __builtin_bit_cast(h2, __builtin_amdgcn_cvt_pkrtz(D[2], D[3]));
        h2 t  = __builtin_elementwise_min(__builtin_elementwise_max(tr, LO), HI);
        h2 u = t * t;
        h2 v = u * IVU;
        h2 P = __builtin_elementwise_fma(C4, v, C3);
        P = __builtin_elementwise_fma(P, v, C2);
        P = __builtin_elementwise_fma(P, v, C1);
        P = __builtin_elementwise_fma(P, v, C0);
        h2 E = t * P;
        h2 m = WB * tr;
        sh = __builtin_elementwise_fma(m, E, sh + m);
    }
    return (float)sh.x + (float)sh.y;
}

// ---------------- host: deg-4 LSQ fit of erf(t/sqrt2) ~ t*P(v), v=t^2/umax ----------------
static void fit_gelu_poly(float cf[5]) {
    const int NS = 512;
    const int M = 5;
    const double umax = (double)GCLAMP * (double)GCLAMP;
    double AtA[5][5], Atb[5];
    for (int i = 0; i < M; ++i) { Atb[i] = 0.0; for (int j = 0; j < M; ++j) AtA[i][j] = 0.0; }
    for (int k = 0; k <= NS; ++k) {
        double u = umax * 0.5 * (1.0 - cos(3.14159265358979323846 * (double)k / NS));
        double t = sqrt(u);
        double g = erf(t * 0.7071067811865476);
        double v = u / umax;
        double phi[5];
        double p = t;
        for (int j = 0; j < M; ++j) { phi[j] = p; p *= v; }
        for (int i = 0; i < M; ++i) {
            Atb[i] += phi[i] * g;
            for (int j = 0; j < M; ++j) AtA[i][j] += phi[i] * phi[j];
        }
    }
    for (int col = 0; col < M; ++col) {              // GE w/ partial pivoting
        int piv = col;
        for (int r = col + 1; r < M; ++r)
            if (fabs(AtA[r][col]) > fabs(AtA[piv][col])) piv = r;
        if (piv != col) {
            for (int j = 0; j < M; ++j) { double tm = AtA[col][j]; AtA[col][j] = AtA[piv][j]; AtA[piv][j] = tm; }
            double tb = Atb[col]; Atb[col] = Atb[piv]; Atb[piv] = tb;
        }
        double d = AtA[col][col];
        for (int r = col + 1; r < M; ++r) {
            double f = AtA[r][col] / d;
            for (int j = col; j < M; ++j) AtA[r][j] -= f * AtA[col][j];
            Atb[r] -= f * Atb[col];
        }
    }
    double c[5];
    for (int i = M - 1; i >= 0; --i) {
        double s = Atb[i];
        for (int j = i + 1; j < M; ++j) s -= AtA[i][j] * c[j];
        c[i] = s / AtA[i][i];
    }
    for (int j = 0; j < M; ++j) cf[j] = (float)c[j];  // v-basis, O(0.01..0.8): fp16-safe
}

// ---------------- binding encoder ----------------
__global__ __launch_bounds__(256) void k_binding(const float* __restrict__ x,
                                                 const float* __restrict__ role,
                                                 const float* __restrict__ fw,
                                                 float* __restrict__ h) {
    int idx = blockIdx.x * 256 + threadIdx.x;        // B*C*D = 1048576
    int d  = idx & 63;
    int bc = idx >> 6;
    float xl = log1pf(fmaxf(x[bc], 0.0f));
    float f  = gelu_f(xl * fw[d]);
    h[idx] = role[(bc & (CC - 1)) * DD + d] * f;
}

// ---------------- QKV projection + Aq (=qp+b1) precompute ----------------
__global__ __launch_bounds__(256) void k_qkv(const float* __restrict__ h,
                                             const float* __restrict__ qw, const float* __restrict__ qb,
                                             const float* __restrict__ kw, const float* __restrict__ kb,
                                             const float* __restrict__ vw, const float* __restrict__ vb,
                                             const float* __restrict__ w1, const float* __restrict__ b1,
                                             float* __restrict__ Q, float* __restrict__ K,
                                             float* __restrict__ V, float* __restrict__ A) {
    __shared__ __attribute__((aligned(16))) float hrow[4][64];
    __shared__ float qrow[4][64];
    int r  = threadIdx.x >> 6;
    int j  = threadIdx.x & 63;
    int bc = blockIdx.x * 4 + r;                     // 0..16383
    hrow[r][j] = h[(size_t)bc * 64 + j];
    __syncthreads();
    float aq = qb[j], ak = kb[j], av = vb[j];
    const float4* hr4 = (const float4*)hrow[r];
    const float4* qw4 = (const float4*)(qw + j * 64);
    const float4* kw4 = (const float4*)(kw + j * 64);
    const float4* vw4 = (const float4*)(vw + j * 64);
    #pragma unroll
    for (int i = 0; i < 16; ++i) {
        float4 hv = hr4[i];
        float4 a = qw4[i], b = kw4[i], c = vw4[i];
        aq = fmaf(hv.x, a.x, fmaf(hv.y, a.y, fmaf(hv.z, a.z, fmaf(hv.w, a.w, aq))));
        ak = fmaf(hv.x, b.x, fmaf(hv.y, b.y, fmaf(hv.z, b.z, fmaf(hv.w, b.w, ak))));
        av = fmaf(hv.x, c.x, fmaf(hv.y, c.y, fmaf(hv.z, c.z, fmaf(hv.w, c.w, av))));
    }
    int head = j >> 4, dh = j & 15;
    int b = bc >> 11, c = bc & (CC - 1);
    size_t o = ((size_t)(b * HH + head) * CC + c) * DHH + dh;
    Q[o] = aq; K[o] = ak; V[o] = av;
    qrow[r][j] = aq;
    __syncthreads();
    float aA = b1[dh];
    #pragma unroll
    for (int i = 0; i < 16; ++i)
        aA = fmaf(qrow[r][head * 16 + i], w1[dh * 48 + i], aA);
    A[o] = aA;
}

// ---------------- MFMA attention with MLP scores (round-15 config + fp16 score acc) ----------------
// grid: qt(128, 16 queries each) x bh(32) = 4096 blocks, 4 waves/block, 4 q/wave.
// (256,6): the unique spill-free point (round-15: WRITE==AT exactly, 68% occ).
// Round-16 (8 q/wave) re-spilled -> reverted. This round: score linear term moved
// to packed fp16 (-6 instr/q of ~82) + w2h[4] regs -> 2 h2 regs.
__global__ __launch_bounds__(256, 6) void k_attn(const float* __restrict__ Q, const float* __restrict__ K,
                                                 const float* __restrict__ V, const float* __restrict__ A,
                                                 const float* __restrict__ w1g, const float* __restrict__ w2g,
                                                 float* __restrict__ AT,
                                                 float c0, float c1, float c2, float c3, float c4) {
    __shared__ __attribute__((aligned(16))) _Float16 Kl[32 * KPAD];   // [key][i0..15,16=1,17..=0]
    __shared__ __attribute__((aligned(16))) _Float16 Vt[16 * KPAD];   // [d][key]
    __shared__ __attribute__((aligned(16))) _Float16 El[4][16 * KPAD];// per wave [q][key]

    int tid  = threadIdx.x;
    int lane = tid & 63;
    int w    = tid >> 6;
    int quad = lane >> 4;
    int l15  = lane & 15;
    int qt = blockIdx.x & 127;
    int bh = blockIdx.x >> 7;
    size_t base = (size_t)bh * (CC * DHH);
    int qbase = qt * 16 + w * 4;

    // one-time: Kl const region ([16]=1, rest 0) + zero ALL of El (rows 4..15 stay 0)
    for (int idx = tid; idx < 32 * 24; idx += 256) {
        int row = idx / 24, off = 16 + idx % 24;
        Kl[row * KPAD + off] = (off == 16) ? (_Float16)1.0f : (_Float16)0.0f;
    }
    {
        _Float16* Elf = &El[0][0];
        for (int idx = tid; idx < 4 * 16 * KPAD; idx += 256) Elf[idx] = (_Float16)0.0f;
    }

    // gelu poly constants (half2)
    h2 C0 = {(_Float16)c0, (_Float16)c0};
    h2 C1 = {(_Float16)c1, (_Float16)c1};
    h2 C2 = {(_Float16)c2, (_Float16)c2};
    h2 C3 = {(_Float16)c3, (_Float16)c3};
    h2 C4 = {(_Float16)c4, (_Float16)c4};
    const float ivu_f = 1.0f / (GCLAMP * GCLAMP);
    h2 IVU = {(_Float16)ivu_f, (_Float16)ivu_f};
    h2 LO = {(_Float16)(-GCLAMP), (_Float16)(-GCLAMP)};
    h2 HI = {(_Float16)GCLAMP, (_Float16)GCLAMP};

    // per-lane w2 pairs for rows j = quad*4+{0..3}; fold 1/sqrt(16)*log2(e)*0.5
    const float wscale = 0.25f * 1.44269504f * 0.5f;
    h2 WA = {(_Float16)(w2g[quad * 4 + 0] * wscale), (_Float16)(w2g[quad * 4 + 1] * wscale)};
    h2 WB = {(_Float16)(w2g[quad * 4 + 2] * wscale), (_Float16)(w2g[quad * 4 + 3] * wscale)};

    bool sel_hi = (lane & 16) != 0;                  // quads 1,3 -> sub1 value at store

    // Bq A-frags: m=j=lane&15, kdim=i=quad*8+jj. quads0,1: W1qk[j][i]*q[i]+W1k[j][i];
    // quad2 jj=0: Aq[j]; else 0. 4 frags (16 regs) live across the K loop.
    half8 bq[4];
    {
        int j = l15;
        #pragma unroll
        for (int q = 0; q < 4; ++q) {
            const float* qv = Q + base + (size_t)(qbase + q) * 16;
            float aqv = A[base + (size_t)(qbase + q) * 16 + j];
            half8 v;
            #pragma unroll
            for (int jj = 0; jj < 8; ++jj) {
                float val;
                if (quad < 2) {
                    int i = quad * 8 + jj;
                    val = fmaf(w1g[j * 48 + 32 + i], qv[i], w1g[j * 48 + 16 + i]);
                } else if (quad == 2 && jj == 0) {
                    val = aqv;
                } else {
                    val = 0.0f;
                }
                v[jj] = (_Float16)val;
            }
            bq[q] = v;
        }
    }

    half8 ones;
    #pragma unroll
    for (int jj = 0; jj < 8; ++jj) ones[jj] = (_Float16)1.0f;
    f32x4 Oc = {0.f, 0.f, 0.f, 0.f};
    f32x4 Dn = {0.f, 0.f, 0.f, 0.f};
    f32x4 zc = {0.f, 0.f, 0.f, 0.f};

    _Float16* Ew = El[w];

    // staging index map (fixed per thread)
    int skey = tid >> 3, sip = (tid & 7) * 2;        // K: thread -> (key, elem-pair)
    int vk0 = tid >> 4,          vd0 = tid & 15;     // V elem 0
    int vk1 = (tid + 256) >> 4,  vd1 = tid & 15;     // V elem 1

    #pragma unroll 1
    for (int t0 = 0; t0 < CC; t0 += 32) {
        __syncthreads();                              // prior tile's LDS readers done
        {   // stage K/V directly (short live ranges; no cross-iteration prefetch regs)
            float2 kv = *(const float2*)(K + base + (size_t)(t0 + skey) * 16 + sip);
            Kl[skey * KPAD + sip]     = (_Float16)kv.x;
            Kl[skey * KPAD + sip + 1] = (_Float16)kv.y;
            Vt[vd0 * KPAD + vk0] = (_Float16)V[base + (size_t)(t0 + vk0) * 16 + vd0];
            Vt[vd1 * KPAD + vk1] = (_Float16)V[base + (size_t)(t0 + vk1) * 16 + vd1];
        }
        __syncthreads();                              // staging visible to all waves

        half8 bK0 = *(const half8*)&Kl[l15 * KPAD + quad * 8];
        half8 bK1 = *(const half8*)&Kl[(16 + l15) * KPAD + quad * 8];

        #pragma unroll
        for (int q = 0; q < 4; ++q) {
            float s0, s1;
            {   // sub0: MFMA + score chain (D0 dies before D1 is produced)
                f32x4 D0 = __builtin_amdgcn_mfma_f32_16x16x32_f16(bq[q], bK0, zc, 0, 0, 0);
                s0 = score_sub(D0, WA, WB, C0, C1, C2, C3, C4, IVU, LO, HI);
            }
            {   // sub1
                f32x4 D1 = __builtin_amdgcn_mfma_f32_16x16x32_f16(bq[q], bK1, zc, 0, 0, 0);
                s1 = score_sub(D1, WA, WB, C0, C1, C2, C3, C4, IVU, LO, HI);
            }
            s0 += __shfl_xor(s0, 16, 64);
            s0 += __shfl_xor(s0, 32, 64);
            s1 += __shfl_xor(s1, 16, 64);
            s1 += __shfl_xor(s1, 32, 64);
            float uu = sel_hi ? s1 : s0;              // lanes 16..31 carry sub1
            float e = EXP2F(uu);                      // base-2 softmax (log2e folded in W)
            if (lane < 32) Ew[q * KPAD + lane] = (_Float16)e;
        }
        // E·V numerator + E·ones denominator (A rows 4..15 are zero -> inert)
        half8 aE = *(const half8*)&Ew[l15 * KPAD + quad * 8];
        half8 bV = *(const half8*)&Vt[l15 * KPAD + quad * 8];
        Oc = __builtin_amdgcn_mfma_f32_16x16x32_f16(aE, bV, Oc, 0, 0, 0);
        Dn = __builtin_amdgcn_mfma_f32_16x16x32_f16(aE, ones, Dn, 0, 0, 0);
    }

    // D layout: row(q)=quad*4+r, col(d)=lane&15; only rows 0..3 (quad==0) are real q's
    int b = bh >> 2, hh = bh & 3;
    if (quad == 0) {
        #pragma unroll
        for (int r = 0; r < 4; ++r) {
            int c = qbase + r;
            AT[((size_t)(b * CC + c)) * DD + hh * 16 + l15] = Oc[r] / Dn[r];
        }
    }
}

// ---------------- fused post-attention: oproj + LN1 + FFN + LN2 (4 rows/block) ----------------
__global__ __launch_bounds__(256) void k_post(const float* __restrict__ AT,
                                              const float* __restrict__ ow, const float* __restrict__ ob,
                                              const float* __restrict__ g1, const float* __restrict__ be1,
                                              const float* __restrict__ f1w, const float* __restrict__ f1b,
                                              const float* __restrict__ f2w, const float* __restrict__ f2b,
                                              const float* __restrict__ g2, const float* __restrict__ be2,
                                              float* __restrict__ h) {
    int bc0 = blockIdx.x * 4;
    int t  = threadIdx.x;
    int j = t & 63, wv = t >> 6;
    __shared__ __attribute__((aligned(16))) float ar[4][64];
    __shared__ __attribute__((aligned(16))) float hln[4][64];
    __shared__ __attribute__((aligned(16))) float u[4][256];
    __shared__ float parts[4][4][64];                // [row][chunk][j]
    ar[wv][j] = AT[(size_t)(bc0 + wv) * 64 + j];
    __syncthreads();
    {   // out-proj partials: thread (wv=chunk, j=out) for all 4 rows
        float p0 = 0.f, p1 = 0.f, p2 = 0.f, p3 = 0.f;
        const float4* w4 = (const float4*)(ow + j * 64 + wv * 16);
        const float4* a0 = (const float4*)(ar[0] + wv * 16);
        const float4* a1 = (const float4*)(ar[1] + wv * 16);
        const float4* a2 = (const float4*)(ar[2] + wv * 16);
        const float4* a3 = (const float4*)(ar[3] + wv * 16);
        #pragma unroll
        for (int i = 0; i < 4; ++i) {
            float4 wvv = w4[i];
            float4 x0 = a0[i], x1 = a1[i], x2 = a2[i], x3 = a3[i];
            p0 = fmaf(x0.x, wvv.x, fmaf(x0.y, wvv.y, fmaf(x0.z, wvv.z, fmaf(x0.w, wvv.w, p0))));
            p1 = fmaf(x1.x, wvv.x, fmaf(x1.y, wvv.y, fmaf(x1.z, wvv.z, fmaf(x1.w, wvv.w, p1))));
            p2 = fmaf(x2.x, wvv.x, fmaf(x2.y, wvv.y, fmaf(x2.z, wvv.z, fmaf(x2.w, wvv.w, p2))));
            p3 = fmaf(x3.x, wvv.x, fmaf(x3.y, wvv.y, fmaf(x3.z, wvv.z, fmaf(x3.w, wvv.w, p3))));
        }
        parts[0][wv][j] = p0; parts[1][wv][j] = p1; parts[2][wv][j] = p2; parts[3][wv][j] = p3;
    }
    __syncthreads();
    {   // LN1: wave wv handles row wv
        float o = ob[j] + parts[wv][0][j] + parts[wv][1][j] + parts[wv][2][j] + parts[wv][3][j];
        float x = h[(size_t)(bc0 + wv) * 64 + j] + o;
        float m  = wave_sum64(x) * (1.0f / 64.0f);
        float dv = x - m;
        float vv = wave_sum64(dv * dv) * (1.0f / 64.0f);
        float r  = __builtin_amdgcn_rsqf(vv + 1e-5f);
        hln[wv][j] = fmaf(dv * r, g1[j], be1[j]);
    }
    __syncthreads();
    {   // FFN1: thread t computes hidden unit t for all 4 rows (weights loaded once)
        float b = f1b[t];
        float a0 = b, a1 = b, a2 = b, a3 = b;
        const float4* w4 = (const float4*)(f1w + t * 64);
        const float4* h0 = (const float4*)hln[0];
        const float4* h1 = (const float4*)hln[1];
        const float4* h2p = (const float4*)hln[2];
        const float4* h3 = (const float4*)hln[3];
        #pragma unroll
        for (int i = 0; i < 16; ++i) {
            float4 wvv = w4[i];
            float4 x0 = h0[i], x1 = h1[i], x2 = h2p[i], x3 = h3[i];
            a0 = fmaf(x0.x, wvv.x, fmaf(x0.y, wvv.y, fmaf(x0.z, wvv.z, fmaf(x0.w, wvv.w, a0))));
            a1 = fmaf(x1.x, wvv.x, fmaf(x1.y, wvv.y, fmaf(x1.z, wvv.z, fmaf(x1.w, wvv.w, a1))));
            a2 = fmaf(x2.x, wvv.x, fmaf(x2.y, wvv.y, fmaf(x2.z, wvv.z, fmaf(x2.w, wvv.w, a2))));
            a3 = fmaf(x3.x, wvv.x, fmaf(x3.y, wvv.y, fmaf(x3.z, wvv.z, fmaf(x3.w, wvv.w, a3))));
        }
        u[0][t] = gelu_f(a0); u[1][t] = gelu_f(a1); u[2][t] = gelu_f(a2); u[3][t] = gelu_f(a3);
    }
    __syncthreads();
    {   // FFN2 partials
        float p0 = 0.f, p1 = 0.f, p2 = 0.f, p3 = 0.f;
        const float4* w4 = (const float4*)(f2w + j * 256 + wv * 64);
        const float4* u0 = (const float4*)(u[0] + wv * 64);
        const float4* u1 = (const float4*)(u[1] + wv * 64);
        const float4* u2 = (const float4*)(u[2] + wv * 64);
        const float4* u3 = (const float4*)(u[3] + wv * 64);
        #pragma unroll
        for (int i = 0; i < 16; ++i) {
            float4 wvv = w4[i];
            float4 x0 = u0[i], x1 = u1[i], x2 = u2[i], x3 = u3[i];
            p0 = fmaf(x0.x, wvv.x, fmaf(x0.y, wvv.y, fmaf(x0.z, wvv.z, fmaf(x0.w, wvv.w, p0))));
            p1 = fmaf(x1.x, wvv.x, fmaf(x1.y, wvv.y, fmaf(x1.z, wvv.z, fmaf(x1.w, wvv.w, p1))));
            p2 = fmaf(x2.x, wvv.x, fmaf(x2.y, wvv.y, fmaf(x2.z, wvv.z, fmaf(x2.w, wvv.w, p2))));
            p3 = fmaf(x3.x, wvv.x, fmaf(x3.y, wvv.y, fmaf(x3.z, wvv.z, fmaf(x3.w, wvv.w, p3))));
        }
        parts[0][wv][j] = p0; parts[1][wv][j] = p1; parts[2][wv][j] = p2; parts[3][wv][j] = p3;
    }
    __syncthreads();
    {   // LN2: wave wv handles row wv
        float o = f2b[j] + parts[wv][0][j] + parts[wv][1][j] + parts[wv][2][j] + parts[wv][3][j];
        float x = hln[wv][j] + o;
        float m  = wave_sum64(x) * (1.0f / 64.0f);
        float dv = x - m;
        float vv = wave_sum64(dv * dv) * (1.0f / 64.0f);
        float r  = __builtin_amdgcn_rsqf(vv + 1e-5f);
        h[(size_t)(bc0 + wv) * 64 + j] = fmaf(dv * r, g2[j], be2[j]);
    }
}

// ---------------- task-query readout ----------------
__global__ __launch_bounds__(256) void k_readout(const float* __restrict__ h,
                                                 const float* __restrict__ tq,
                                                 const float* __restrict__ hw, const float* __restrict__ hb,
                                                 float* __restrict__ out) {
    int b = blockIdx.x;
    int t = threadIdx.x;
    __shared__ float ebuf[2048];
    __shared__ float tqs[64];
    __shared__ float sred[256];
    __shared__ float red[4][64];
    if (t < 64) tqs[t] = tq[t];
    __syncthreads();
    float ss = 0.0f;
    for (int c = t; c < CC; c += 256) {
        const float* hrow = h + ((size_t)b * CC + c) * 64;
        float s = 0.0f;
        #pragma unroll
        for (int d = 0; d < 64; ++d) s = fmaf(hrow[d], tqs[d], s);
        float e = __expf(s * 0.125f);                 // scores ~ +-0.1: max-free safe
        ebuf[c] = e; ss += e;
    }
    sred[t] = ss;
    __syncthreads();
    for (int o = 128; o; o >>= 1) {
        if (t < o) sred[t] += sred[t + o];
        __syncthreads();
    }
    float inv = 1.0f / sred[0];
    int d = t & 63, ch = t >> 6;
    float p = 0.0f;
    for (int c = ch * 512; c < ch * 512 + 512; ++c)
        p = fmaf(ebuf[c], h[((size_t)b * CC + c) * 64 + d], p);
    red[ch][d] = p;
    __syncthreads();
    if (t < 64) red[0][t] = (red[0][t] + red[1][t] + red[2][t] + red[3][t]) * inv;
    __syncthreads();
    if (t < 10) {
        float o = hb[t];
        #pragma unroll
        for (int d2 = 0; d2 < 64; ++d2) o = fmaf(red[0][d2], hw[t * 64 + d2], o);
        out[b * 10 + t] = o;
    }
}

extern "C" void kernel_launch(void* const* d_in, const int* in_sizes, int n_in,
                              void* d_out, int out_size, void* d_ws, size_t ws_size,
                              hipStream_t stream) {
    (void)in_sizes; (void)n_in; (void)out_size; (void)ws_size;
    const float* x    = (const float*)d_in[0];
    const float* role = (const float*)d_in[1];
    const float* fw   = (const float*)d_in[2];
    const float* qw   = (const float*)d_in[3];
    const float* qb   = (const float*)d_in[4];
    const float* kw   = (const float*)d_in[5];
    const float* kb   = (const float*)d_in[6];
    const float* vw   = (const float*)d_in[7];
    const float* vb   = (const float*)d_in[8];
    const float* w1   = (const float*)d_in[9];
    const float* b1   = (const float*)d_in[10];
    const float* w2   = (const float*)d_in[11];
    // d_in[12] = b2: softmax-shift-invariant, dropped
    const float* ow   = (const float*)d_in[13];
    const float* ob   = (const float*)d_in[14];
    const float* g1   = (const float*)d_in[15];
    const float* be1  = (const float*)d_in[16];
    const float* f1w  = (const float*)d_in[17];
    const float* f1b  = (const float*)d_in[18];
    const float* f2w  = (const float*)d_in[19];
    const float* f2b  = (const float*)d_in[20];
    const float* g2   = (const float*)d_in[21];
    const float* be2  = (const float*)d_in[22];
    const float* tq   = (const float*)d_in[23];
    const float* hw   = (const float*)d_in[24];
    const float* hb   = (const float*)d_in[25];

    float cf[5];
    fit_gelu_poly(cf);                               // deterministic per call (~us, host-only)

    float* ws   = (float*)d_ws;
    const size_t M = 1048576;                        // B*C*D
    float* H    = ws;
    float* Q    = ws + 1 * M;
    float* K    = ws + 2 * M;
    float* V    = ws + 3 * M;
    float* Abuf = ws + 4 * M;
    float* AT   = ws + 5 * M;

    k_binding<<<4096, 256, 0, stream>>>(x, role, fw, H);
    for (int l = 0; l < LL; ++l) {
        k_qkv<<<4096, 256, 0, stream>>>(H, qw + l * 4096, qb + l * 64, kw + l * 4096, kb + l * 64,
                                        vw + l * 4096, vb + l * 64, w1 + l * 768, b1 + l * 16,
                                        Q, K, V, Abuf);
        k_attn<<<4096, 256, 0, stream>>>(Q, K, V, Abuf, w1 + l * 768, w2 + l * 16, AT,
                                         cf[0], cf[1], cf[2], cf[3], cf[4]);
        k_post<<<4096, 256, 0, stream>>>(AT, ow + l * 4096, ob + l * 64, g1 + l * 64, be1 + l * 64,
                                         f1w + l * 16384, f1b + l * 256, f2w + l * 16384,
                                         f2b + l * 64, g2 + l * 64, be2 + l * 64, H);
    }
    k_readout<<<8, 256, 0, stream>>>(H, tq, hw, hb, (float*)d_out);
}

// Round 18
// 2415.596 us; speedup vs baseline: 1.1099x; 1.0319x over previous
//
#include <hip/hip_runtime.h>
#include <math.h>
#include <cmath>

// Problem constants
#define BB 8
#define CC 2048
#define DD 64
#define LL 3
#define HH 4
#define DHH 16
#define KPAD 40   // halves per Kl/El row: 32 + 8 pad (80B)
#define VPAD 72   // halves per Vt row: 64 keys + 8 pad
#define GCLAMP 4.25f

typedef _Float16 half8 __attribute__((ext_vector_type(8)));
typedef _Float16 h2    __attribute__((ext_vector_type(2)));
typedef float f32x4 __attribute__((ext_vector_type(4)));

#if defined(__has_builtin)
#if __has_builtin(__builtin_amdgcn_exp2f)
#define EXP2F(x) __builtin_amdgcn_exp2f(x)
#else
#define EXP2F(x) __expf((x) * 0.693147180559945f)
#endif
#else
#define EXP2F(x) __expf((x) * 0.693147180559945f)
#endif

// ---------------- exact GELU via A&S 7.1.26 erf (residual-path kernels) ----------------
__device__ __forceinline__ float gelu_f(float x) {
    float z  = 0.70710678118654752f * x;
    float az = fabsf(z);
    float t  = __builtin_amdgcn_rcpf(fmaf(0.3275911f, az, 1.0f));
    float p  = t * fmaf(t, fmaf(t, fmaf(t, fmaf(t, 1.061405429f, -1.453152027f),
                                        1.421413741f), -0.284496736f), 0.254829592f);
    float e  = __expf(-z * z);
    float r  = p * e;                                // erfc(|z|)
    float phi = (x >= 0.0f) ? fmaf(-0.5f, r, 1.0f) : 0.5f * r;
    return x * phi;
}

__device__ __forceinline__ float wave_sum64(float v) {
    #pragma unroll
    for (int off = 32; off; off >>= 1) v += __shfl_xor(v, off, 64);
    return v;
}

// ---------------- fully-fp16 packed erf-GELU score for one f32x4 sub-tile ----------------
__device__ __forceinline__ float score_sub(f32x4 D, h2 WA, h2 WB,
                                           h2 C0, h2 C1, h2 C2, h2 C3, h2 C4,
                                           h2 IVU, h2 LO, h2 HI) {
    h2 sh = {(_Float16)0.0f, (_Float16)0.0f};
    {
        h2 tr = __builtin_bit_cast(h2, __builtin_amdgcn_cvt_pkrtz(D[0], D[1]));
        h2 t  = __builtin_elementwise_min(__builtin_elementwise_max(tr, LO), HI);
        h2 u = t * t;
        h2 v = u * IVU;
        h2 P = __builtin_elementwise_fma(C4, v, C3);
        P = __builtin_elementwise_fma(P, v, C2);
        P = __builtin_elementwise_fma(P, v, C1);
        P = __builtin_elementwise_fma(P, v, C0);
        h2 E = t * P;
        h2 m = WA * tr;
        sh = __builtin_elementwise_fma(m, E, sh + m);
    }
    {
        h2 tr = __builtin_bit_cast(h2, __builtin_amdgcn_cvt_pkrtz(D[2], D[3]));
        h2 t  = __builtin_elementwise_min(__builtin_elementwise_max(tr, LO), HI);
        h2 u = t * t;
        h2 v = u * IVU;
        h2 P = __builtin_elementwise_fma(C4, v, C3);
        P = __builtin_elementwise_fma(P, v, C2);
        P = __builtin_elementwise_fma(P, v, C1);
        P = __builtin_elementwise_fma(P, v, C0);
        h2 E = t * P;
        h2 m = WB * tr;
        sh = __builtin_elementwise_fma(m, E, sh + m);
    }
    return (float)sh.x + (float)sh.y;
}

// ---------------- host: deg-4 LSQ fit of erf(t/sqrt2) ~ t*P(v), v=t^2/umax ----------------
static void fit_gelu_poly(float cf[5]) {
    const int NS = 512;
    const int M = 5;
    const double umax = (double)GCLAMP * (double)GCLAMP;
    double AtA[5][5], Atb[5];
    for (int i = 0; i < M; ++i) { Atb[i] = 0.0; for (int j = 0; j < M; ++j) AtA[i][j] = 0.0; }
    for (int k = 0; k <= NS; ++k) {
        double u = umax * 0.5 * (1.0 - cos(3.14159265358979323846 * (double)k / NS));
        double t = sqrt(u);
        double g = erf(t * 0.7071067811865476);
        double v = u / umax;
        double phi[5];
        double p = t;
        for (int j = 0; j < M; ++j) { phi[j] = p; p *= v; }
        for (int i = 0; i < M; ++i) {
            Atb[i] += phi[i] * g;
            for (int j = 0; j < M; ++j) AtA[i][j] += phi[i] * phi[j];
        }
    }
    for (int col = 0; col < M; ++col) {              // GE w/ partial pivoting
        int piv = col;
        for (int r = col + 1; r < M; ++r)
            if (fabs(AtA[r][col]) > fabs(AtA[piv][col])) piv = r;
        if (piv != col) {
            for (int j = 0; j < M; ++j) { double tm = AtA[col][j]; AtA[col][j] = AtA[piv][j]; AtA[piv][j] = tm; }
            double tb = Atb[col]; Atb[col] = Atb[piv]; Atb[piv] = tb;
        }
        double d = AtA[col][col];
        for (int r = col + 1; r < M; ++r) {
            double f = AtA[r][col] / d;
            for (int j = col; j < M; ++j) AtA[r][j] -= f * AtA[col][j];
            Atb[r] -= f * Atb[col];
        }
    }
    double c[5];
    for (int i = M - 1; i >= 0; --i) {
        double s = Atb[i];
        for (int j = i + 1; j < M; ++j) s -= AtA[i][j] * c[j];
        c[i] = s / AtA[i][i];
    }
    for (int j = 0; j < M; ++j) cf[j] = (float)c[j];  // v-basis, O(0.01..0.8): fp16-safe
}

// ---------------- binding encoder ----------------
__global__ __launch_bounds__(256) void k_binding(const float* __restrict__ x,
                                                 const float* __restrict__ role,
                                                 const float* __restrict__ fw,
                                                 float* __restrict__ h) {
    int idx = blockIdx.x * 256 + threadIdx.x;        // B*C*D = 1048576
    int d  = idx & 63;
    int bc = idx >> 6;
    float xl = log1pf(fmaxf(x[bc], 0.0f));
    float f  = gelu_f(xl * fw[d]);
    h[idx] = role[(bc & (CC - 1)) * DD + d] * f;
}

// ---------------- QKV projection + Aq (=qp+b1) precompute ----------------
__global__ __launch_bounds__(256) void k_qkv(const float* __restrict__ h,
                                             const float* __restrict__ qw, const float* __restrict__ qb,
                                             const float* __restrict__ kw, const float* __restrict__ kb,
                                             const float* __restrict__ vw, const float* __restrict__ vb,
                                             const float* __restrict__ w1, const float* __restrict__ b1,
                                             float* __restrict__ Q, float* __restrict__ K,
                                             float* __restrict__ V, float* __restrict__ A) {
    __shared__ __attribute__((aligned(16))) float hrow[4][64];
    __shared__ float qrow[4][64];
    int r  = threadIdx.x >> 6;
    int j  = threadIdx.x & 63;
    int bc = blockIdx.x * 4 + r;                     // 0..16383
    hrow[r][j] = h[(size_t)bc * 64 + j];
    __syncthreads();
    float aq = qb[j], ak = kb[j], av = vb[j];
    const float4* hr4 = (const float4*)hrow[r];
    const float4* qw4 = (const float4*)(qw + j * 64);
    const float4* kw4 = (const float4*)(kw + j * 64);
    const float4* vw4 = (const float4*)(vw + j * 64);
    #pragma unroll
    for (int i = 0; i < 16; ++i) {
        float4 hv = hr4[i];
        float4 a = qw4[i], b = kw4[i], c = vw4[i];
        aq = fmaf(hv.x, a.x, fmaf(hv.y, a.y, fmaf(hv.z, a.z, fmaf(hv.w, a.w, aq))));
        ak = fmaf(hv.x, b.x, fmaf(hv.y, b.y, fmaf(hv.z, b.z, fmaf(hv.w, b.w, ak))));
        av = fmaf(hv.x, c.x, fmaf(hv.y, c.y, fmaf(hv.z, c.z, fmaf(hv.w, c.w, av))));
    }
    int head = j >> 4, dh = j & 15;
    int b = bc >> 11, c = bc & (CC - 1);
    size_t o = ((size_t)(b * HH + head) * CC + c) * DHH + dh;
    Q[o] = aq; K[o] = ak; V[o] = av;
    qrow[r][j] = aq;
    __syncthreads();
    float aA = b1[dh];
    #pragma unroll
    for (int i = 0; i < 16; ++i)
        aA = fmaf(qrow[r][head * 16 + i], w1[dh * 48 + i], aA);
    A[o] = aA;
}

// ---------------- MFMA attention (64-key tiles: half the barriers, float4 staging) ----------------
// grid: qt(128, 16 queries each) x bh(32) = 4096 blocks, 4 waves/block, 4 q/wave.
// El is PER-WAVE -> wave-synchronous, no barrier needed; only Kl/Vt staging needs
// barriers. Staging 64 keys per barrier-pair halves barrier count (128->64/wave) and
// makes staging two coalesced float4 loads/thread. (256,6) remains the spill-free point.
__global__ __launch_bounds__(256, 6) void k_attn(const float* __restrict__ Q, const float* __restrict__ K,
                                                 const float* __restrict__ V, const float* __restrict__ A,
                                                 const float* __restrict__ w1g, const float* __restrict__ w2g,
                                                 float* __restrict__ AT,
                                                 float c0, float c1, float c2, float c3, float c4) {
    __shared__ __attribute__((aligned(16))) _Float16 Kl[64 * KPAD];   // [key][i0..15,16=1,17..=0]
    __shared__ __attribute__((aligned(16))) _Float16 Vt[16 * VPAD];   // [d][key 0..63]
    __shared__ __attribute__((aligned(16))) _Float16 El[4][16 * KPAD];// per wave [q][key-in-half]

    int tid  = threadIdx.x;
    int lane = tid & 63;
    int w    = tid >> 6;
    int quad = lane >> 4;
    int l15  = lane & 15;
    int qt = blockIdx.x & 127;
    int bh = blockIdx.x >> 7;
    size_t base = (size_t)bh * (CC * DHH);
    int qbase = qt * 16 + w * 4;

    // one-time: Kl const region ([16]=1, rest 0) for 64 rows + zero ALL of El
    for (int idx = tid; idx < 64 * 24; idx += 256) {
        int row = idx / 24, off = 16 + idx % 24;
        Kl[row * KPAD + off] = (off == 16) ? (_Float16)1.0f : (_Float16)0.0f;
    }
    {
        _Float16* Elf = &El[0][0];
        for (int idx = tid; idx < 4 * 16 * KPAD; idx += 256) Elf[idx] = (_Float16)0.0f;
    }

    // gelu poly constants (half2)
    h2 C0 = {(_Float16)c0, (_Float16)c0};
    h2 C1 = {(_Float16)c1, (_Float16)c1};
    h2 C2 = {(_Float16)c2, (_Float16)c2};
    h2 C3 = {(_Float16)c3, (_Float16)c3};
    h2 C4 = {(_Float16)c4, (_Float16)c4};
    const float ivu_f = 1.0f / (GCLAMP * GCLAMP);
    h2 IVU = {(_Float16)ivu_f, (_Float16)ivu_f};
    h2 LO = {(_Float16)(-GCLAMP), (_Float16)(-GCLAMP)};
    h2 HI = {(_Float16)GCLAMP, (_Float16)GCLAMP};

    // per-lane w2 pairs for rows j = quad*4+{0..3}; fold 1/sqrt(16)*log2(e)*0.5
    const float wscale = 0.25f * 1.44269504f * 0.5f;
    h2 WA = {(_Float16)(w2g[quad * 4 + 0] * wscale), (_Float16)(w2g[quad * 4 + 1] * wscale)};
    h2 WB = {(_Float16)(w2g[quad * 4 + 2] * wscale), (_Float16)(w2g[quad * 4 + 3] * wscale)};

    bool sel_hi = (lane & 16) != 0;                  // quads 1,3 -> sub1 value at store

    // Bq A-frags: m=j=lane&15, kdim=i=quad*8+jj. quads0,1: W1qk[j][i]*q[i]+W1k[j][i];
    // quad2 jj=0: Aq[j]; else 0. 4 frags (16 regs) live across the K loop.
    half8 bq[4];
    {
        int j = l15;
        #pragma unroll
        for (int q = 0; q < 4; ++q) {
            const float* qv = Q + base + (size_t)(qbase + q) * 16;
            float aqv = A[base + (size_t)(qbase + q) * 16 + j];
            half8 v;
            #pragma unroll
            for (int jj = 0; jj < 8; ++jj) {
                float val;
                if (quad < 2) {
                    int i = quad * 8 + jj;
                    val = fmaf(w1g[j * 48 + 32 + i], qv[i], w1g[j * 48 + 16 + i]);
                } else if (quad == 2 && jj == 0) {
                    val = aqv;
                } else {
                    val = 0.0f;
                }
                v[jj] = (_Float16)val;
            }
            bq[q] = v;
        }
    }

    half8 ones;
    #pragma unroll
    for (int jj = 0; jj < 8; ++jj) ones[jj] = (_Float16)1.0f;
    f32x4 Oc = {0.f, 0.f, 0.f, 0.f};
    f32x4 Dn = {0.f, 0.f, 0.f, 0.f};
    f32x4 zc = {0.f, 0.f, 0.f, 0.f};

    _Float16* Ew = El[w];

    // staging index map: both K and V are one float4 per thread per 64-key tile
    int skey = tid >> 2, sip = (tid & 3) * 4;        // K: (key 0..63, elem 0/4/8/12)
    int vkey = tid >> 2, vd  = (tid & 3) * 4;        // V: (key 0..63, d 0/4/8/12)

    #pragma unroll 1
    for (int t0 = 0; t0 < CC; t0 += 64) {
        __syncthreads();                              // prior tile's LDS readers done
        {   // stage 64 keys of K and V (transposed) with coalesced float4 loads
            float4 kv = *(const float4*)(K + base + (size_t)(t0 + skey) * 16 + sip);
            Kl[skey * KPAD + sip + 0] = (_Float16)kv.x;
            Kl[skey * KPAD + sip + 1] = (_Float16)kv.y;
            Kl[skey * KPAD + sip + 2] = (_Float16)kv.z;
            Kl[skey * KPAD + sip + 3] = (_Float16)kv.w;
            float4 vv = *(const float4*)(V + base + (size_t)(t0 + vkey) * 16 + vd);
            Vt[(vd + 0) * VPAD + vkey] = (_Float16)vv.x;
            Vt[(vd + 1) * VPAD + vkey] = (_Float16)vv.y;
            Vt[(vd + 2) * VPAD + vkey] = (_Float16)vv.z;
            Vt[(vd + 3) * VPAD + vkey] = (_Float16)vv.w;
        }
        __syncthreads();                              // staging visible to all waves

        #pragma unroll
        for (int hf = 0; hf < 2; ++hf) {              // two 32-key halves, no barrier between
            half8 bK0 = *(const half8*)&Kl[(hf * 32 + l15) * KPAD + quad * 8];
            half8 bK1 = *(const half8*)&Kl[(hf * 32 + 16 + l15) * KPAD + quad * 8];

            #pragma unroll
            for (int q = 0; q < 4; ++q) {
                float s0, s1;
                {
                    f32x4 D0 = __builtin_amdgcn_mfma_f32_16x16x32_f16(bq[q], bK0, zc, 0, 0, 0);
                    s0 = score_sub(D0, WA, WB, C0, C1, C2, C3, C4, IVU, LO, HI);
                }
                {
                    f32x4 D1 = __builtin_amdgcn_mfma_f32_16x16x32_f16(bq[q], bK1, zc, 0, 0, 0);
                    s1 = score_sub(D1, WA, WB, C0, C1, C2, C3, C4, IVU, LO, HI);
                }
                s0 += __shfl_xor(s0, 16, 64);
                s0 += __shfl_xor(s0, 32, 64);
                s1 += __shfl_xor(s1, 16, 64);
                s1 += __shfl_xor(s1, 32, 64);
                float uu = sel_hi ? s1 : s0;          // lanes 16..31 carry sub1
                float e = EXP2F(uu);                  // base-2 softmax (log2e folded in W)
                if (lane < 32) Ew[q * KPAD + lane] = (_Float16)e;
            }
            // E·V numerator + E·ones denominator (El rows 4..15 zero -> inert)
            half8 aE = *(const half8*)&Ew[l15 * KPAD + quad * 8];
            half8 bV = *(const half8*)&Vt[l15 * VPAD + hf * 32 + quad * 8];
            Oc = __builtin_amdgcn_mfma_f32_16x16x32_f16(aE, bV, Oc, 0, 0, 0);
            Dn = __builtin_amdgcn_mfma_f32_16x16x32_f16(aE, ones, Dn, 0, 0, 0);
        }
    }

    // D layout: row(q)=quad*4+r, col(d)=lane&15; only rows 0..3 (quad==0) are real q's
    int b = bh >> 2, hh = bh & 3;
    if (quad == 0) {
        #pragma unroll
        for (int r = 0; r < 4; ++r) {
            int c = qbase + r;
            AT[((size_t)(b * CC + c)) * DD + hh * 16 + l15] = Oc[r] / Dn[r];
        }
    }
}

// ---------------- fused post-attention: oproj + LN1 + FFN + LN2 (4 rows/block) ----------------
__global__ __launch_bounds__(256) void k_post(const float* __restrict__ AT,
                                              const float* __restrict__ ow, const float* __restrict__ ob,
                                              const float* __restrict__ g1, const float* __restrict__ be1,
                                              const float* __restrict__ f1w, const float* __restrict__ f1b,
                                              const float* __restrict__ f2w, const float* __restrict__ f2b,
                                              const float* __restrict__ g2, const float* __restrict__ be2,
                                              float* __restrict__ h) {
    int bc0 = blockIdx.x * 4;
    int t  = threadIdx.x;
    int j = t & 63, wv = t >> 6;
    __shared__ __attribute__((aligned(16))) float ar[4][64];
    __shared__ __attribute__((aligned(16))) float hln[4][64];
    __shared__ __attribute__((aligned(16))) float u[4][256];
    __shared__ float parts[4][4][64];                // [row][chunk][j]
    ar[wv][j] = AT[(size_t)(bc0 + wv) * 64 + j];
    __syncthreads();
    {   // out-proj partials: thread (wv=chunk, j=out) for all 4 rows
        float p0 = 0.f, p1 = 0.f, p2 = 0.f, p3 = 0.f;
        const float4* w4 = (const float4*)(ow + j * 64 + wv * 16);
        const float4* a0 = (const float4*)(ar[0] + wv * 16);
        const float4* a1 = (const float4*)(ar[1] + wv * 16);
        const float4* a2 = (const float4*)(ar[2] + wv * 16);
        const float4* a3 = (const float4*)(ar[3] + wv * 16);
        #pragma unroll
        for (int i = 0; i < 4; ++i) {
            float4 wvv = w4[i];
            float4 x0 = a0[i], x1 = a1[i], x2 = a2[i], x3 = a3[i];
            p0 = fmaf(x0.x, wvv.x, fmaf(x0.y, wvv.y, fmaf(x0.z, wvv.z, fmaf(x0.w, wvv.w, p0))));
            p1 = fmaf(x1.x, wvv.x, fmaf(x1.y, wvv.y, fmaf(x1.z, wvv.z, fmaf(x1.w, wvv.w, p1))));
            p2 = fmaf(x2.x, wvv.x, fmaf(x2.y, wvv.y, fmaf(x2.z, wvv.z, fmaf(x2.w, wvv.w, p2))));
            p3 = fmaf(x3.x, wvv.x, fmaf(x3.y, wvv.y, fmaf(x3.z, wvv.z, fmaf(x3.w, wvv.w, p3))));
        }
        parts[0][wv][j] = p0; parts[1][wv][j] = p1; parts[2][wv][j] = p2; parts[3][wv][j] = p3;
    }
    __syncthreads();
    {   // LN1: wave wv handles row wv
        float o = ob[j] + parts[wv][0][j] + parts[wv][1][j] + parts[wv][2][j] + parts[wv][3][j];
        float x = h[(size_t)(bc0 + wv) * 64 + j] + o;
        float m  = wave_sum64(x) * (1.0f / 64.0f);
        float dv = x - m;
        float vv = wave_sum64(dv * dv) * (1.0f / 64.0f);
        float r  = __builtin_amdgcn_rsqf(vv + 1e-5f);
        hln[wv][j] = fmaf(dv * r, g1[j], be1[j]);
    }
    __syncthreads();
    {   // FFN1: thread t computes hidden unit t for all 4 rows (weights loaded once)
        float b = f1b[t];
        float a0 = b, a1 = b, a2 = b, a3 = b;
        const float4* w4 = (const float4*)(f1w + t * 64);
        const float4* h0 = (const float4*)hln[0];
        const float4* h1 = (const float4*)hln[1];
        const float4* h2p = (const float4*)hln[2];
        const float4* h3 = (const float4*)hln[3];
        #pragma unroll
        for (int i = 0; i < 16; ++i) {
            float4 wvv = w4[i];
            float4 x0 = h0[i], x1 = h1[i], x2 = h2p[i], x3 = h3[i];
            a0 = fmaf(x0.x, wvv.x, fmaf(x0.y, wvv.y, fmaf(x0.z, wvv.z, fmaf(x0.w, wvv.w, a0))));
            a1 = fmaf(x1.x, wvv.x, fmaf(x1.y, wvv.y, fmaf(x1.z, wvv.z, fmaf(x1.w, wvv.w, a1))));
            a2 = fmaf(x2.x, wvv.x, fmaf(x2.y, wvv.y, fmaf(x2.z, wvv.z, fmaf(x2.w, wvv.w, a2))));
            a3 = fmaf(x3.x, wvv.x, fmaf(x3.y, wvv.y, fmaf(x3.z, wvv.z, fmaf(x3.w, wvv.w, a3))));
        }
        u[0][t] = gelu_f(a0); u[1][t] = gelu_f(a1); u[2][t] = gelu_f(a2); u[3][t] = gelu_f(a3);
    }
    __syncthreads();
    {   // FFN2 partials
        float p0 = 0.f, p1 = 0.f, p2 = 0.f, p3 = 0.f;
        const float4* w4 = (const float4*)(f2w + j * 256 + wv * 64);
        const float4* u0 = (const float4*)(u[0] + wv * 64);
        const float4* u1 = (const float4*)(u[1] + wv * 64);
        const float4* u2 = (const float4*)(u[2] + wv * 64);
        const float4* u3 = (const float4*)(u[3] + wv * 64);
        #pragma unroll
        for (int i = 0; i < 16; ++i) {
            float4 wvv = w4[i];
            float4 x0 = u0[i], x1 = u1[i], x2 = u2[i], x3 = u3[i];
            p0 = fmaf(x0.x, wvv.x, fmaf(x0.y, wvv.y, fmaf(x0.z, wvv.z, fmaf(x0.w, wvv.w, p0))));
            p1 = fmaf(x1.x, wvv.x, fmaf(x1.y, wvv.y, fmaf(x1.z, wvv.z, fmaf(x1.w, wvv.w, p1))));
            p2 = fmaf(x2.x, wvv.x, fmaf(x2.y, wvv.y, fmaf(x2.z, wvv.z, fmaf(x2.w, wvv.w, p2))));
            p3 = fmaf(x3.x, wvv.x, fmaf(x3.y, wvv.y, fmaf(x3.z, wvv.z, fmaf(x3.w, wvv.w, p3))));
        }
        parts[0][wv][j] = p0; parts[1][wv][j] = p1; parts[2][wv][j] = p2; parts[3][wv][j] = p3;
    }
    __syncthreads();
    {   // LN2: wave wv handles row wv
        float o = f2b[j] + parts[wv][0][j] + parts[wv][1][j] + parts[wv][2][j] + parts[wv][3][j];
        float x = hln[wv][j] + o;
        float m  = wave_sum64(x) * (1.0f / 64.0f);
        float dv = x - m;
        float vv = wave_sum64(dv * dv) * (1.0f / 64.0f);
        float r  = __builtin_amdgcn_rsqf(vv + 1e-5f);
        h[(size_t)(bc0 + wv) * 64 + j] = fmaf(dv * r, g2[j], be2[j]);
    }
}

// ---------------- task-query readout ----------------
__global__ __launch_bounds__(256) void k_readout(const float* __restrict__ h,
                                                 const float* __restrict__ tq,
                                                 const float* __restrict__ hw, const float* __restrict__ hb,
                                                 float* __restrict__ out) {
    int b = blockIdx.x;
    int t = threadIdx.x;
    __shared__ float ebuf[2048];
    __shared__ float tqs[64];
    __shared__ float sred[256];
    __shared__ float red[4][64];
    if (t < 64) tqs[t] = tq[t];
    __syncthreads();
    float ss = 0.0f;
    for (int c = t; c < CC; c += 256) {
        const float* hrow = h + ((size_t)b * CC + c) * 64;
        float s = 0.0f;
        #pragma unroll
        for (int d = 0; d < 64; ++d) s = fmaf(hrow[d], tqs[d], s);
        float e = __expf(s * 0.125f);                 // scores ~ +-0.1: max-free safe
        ebuf[c] = e; ss += e;
    }
    sred[t] = ss;
    __syncthreads();
    for (int o = 128; o; o >>= 1) {
        if (t < o) sred[t] += sred[t + o];
        __syncthreads();
    }
    float inv = 1.0f / sred[0];
    int d = t & 63, ch = t >> 6;
    float p = 0.0f;
    for (int c = ch * 512; c < ch * 512 + 512; ++c)
        p = fmaf(ebuf[c], h[((size_t)b * CC + c) * 64 + d], p);
    red[ch][d] = p;
    __syncthreads();
    if (t < 64) red[0][t] = (red[0][t] + red[1][t] + red[2][t] + red[3][t]) * inv;
    __syncthreads();
    if (t < 10) {
        float o = hb[t];
        #pragma unroll
        for (int d2 = 0; d2 < 64; ++d2) o = fmaf(red[0][d2], hw[t * 64 + d2], o);
        out[b * 10 + t] = o;
    }
}

extern "C" void kernel_launch(void* const* d_in, const int* in_sizes, int n_in,
                              void* d_out, int out_size, void* d_ws, size_t ws_size,
                              hipStream_t stream) {
    (void)in_sizes; (void)n_in; (void)out_size; (void)ws_size;
    const float* x    = (const float*)d_in[0];
    const float* role = (const float*)d_in[1];
    const float* fw   = (const float*)d_in[2];
    const float* qw   = (const float*)d_in[3];
    const float* qb   = (const float*)d_in[4];
    const float* kw   = (const float*)d_in[5];
    const float* kb   = (const float*)d_in[6];
    const float* vw   = (const float*)d_in[7];
    const float* vb   = (const float*)d_in[8];
    const float* w1   = (const float*)d_in[9];
    const float* b1   = (const float*)d_in[10];
    const float* w2   = (const float*)d_in[11];
    // d_in[12] = b2: softmax-shift-invariant, dropped
    const float* ow   = (const float*)d_in[13];
    const float* ob   = (const float*)d_in[14];
    const float* g1   = (const float*)d_in[15];
    const float* be1  = (const float*)d_in[16];
    const float* f1w  = (const float*)d_in[17];
    const float* f1b  = (const float*)d_in[18];
    const float* f2w  = (const float*)d_in[19];
    const float* f2b  = (const float*)d_in[20];
    const float* g2   = (const float*)d_in[21];
    const float* be2  = (const float*)d_in[22];
    const float* tq   = (const float*)d_in[23];
    const float* hw   = (const float*)d_in[24];
    const float* hb   = (const float*)d_in[25];

    float cf[5];
    fit_gelu_poly(cf);                               // deterministic per call (~us, host-only)

    float* ws   = (float*)d_ws;
    const size_t M = 1048576;                        // B*C*D
    float* H    = ws;
    float* Q    = ws + 1 * M;
    float* K    = ws + 2 * M;
    float* V    = ws + 3 * M;
    float* Abuf = ws + 4 * M;
    float* AT   = ws + 5 * M;

    k_binding<<<4096, 256, 0, stream>>>(x, role, fw, H);
    for (int l = 0; l < LL; ++l) {
        k_qkv<<<4096, 256, 0, stream>>>(H, qw + l * 4096, qb + l * 64, kw + l * 4096, kb + l * 64,
                                        vw + l * 4096, vb + l * 64, w1 + l * 768, b1 + l * 16,
                                        Q, K, V, Abuf);
        k_attn<<<4096, 256, 0, stream>>>(Q, K, V, Abuf, w1 + l * 768, w2 + l * 16, AT,
                                         cf[0], cf[1], cf[2], cf[3], cf[4]);
        k_post<<<4096, 256, 0, stream>>>(AT, ow + l * 4096, ob + l * 64, g1 + l * 64, be1 + l * 64,
                                         f1w + l * 16384, f1b + l * 256, f2w + l * 16384,
                                         f2b + l * 64, g2 + l * 64, be2 + l * 64, H);
    }
    k_readout<<<8, 256, 0, stream>>>(H, tq, hw, hb, (float*)d_out);
}

// Round 19
// 2218.852 us; speedup vs baseline: 1.2083x; 1.0887x over previous
//
#include <hip/hip_runtime.h>
#include <math.h>
#include <cmath>

// Problem constants
#define BB 8
#define CC 2048
#define DD 64
#define LL 3
#define HH 4
#define DHH 16
#define KPAD 40   // halves per Kl/El row: 32 + 8 pad (80B)
#define VPAD 72   // halves per Vt row: 64 keys + 8 pad (144B, 16B-aligned)
#define GCLAMP 4.25f

typedef _Float16 half8 __attribute__((ext_vector_type(8)));
typedef _Float16 h2    __attribute__((ext_vector_type(2)));
typedef float f32x4 __attribute__((ext_vector_type(4)));

#if defined(__has_builtin)
#if __has_builtin(__builtin_amdgcn_exp2f)
#define EXP2F(x) __builtin_amdgcn_exp2f(x)
#else
#define EXP2F(x) __expf((x) * 0.693147180559945f)
#endif
#else
#define EXP2F(x) __expf((x) * 0.693147180559945f)
#endif

// ---------------- exact GELU via A&S 7.1.26 erf (residual-path kernels) ----------------
__device__ __forceinline__ float gelu_f(float x) {
    float z  = 0.70710678118654752f * x;
    float az = fabsf(z);
    float t  = __builtin_amdgcn_rcpf(fmaf(0.3275911f, az, 1.0f));
    float p  = t * fmaf(t, fmaf(t, fmaf(t, fmaf(t, 1.061405429f, -1.453152027f),
                                        1.421413741f), -0.284496736f), 0.254829592f);
    float e  = __expf(-z * z);
    float r  = p * e;                                // erfc(|z|)
    float phi = (x >= 0.0f) ? fmaf(-0.5f, r, 1.0f) : 0.5f * r;
    return x * phi;
}

__device__ __forceinline__ float wave_sum64(float v) {
    #pragma unroll
    for (int off = 32; off; off >>= 1) v += __shfl_xor(v, off, 64);
    return v;
}

// ---------------- fully-fp16 packed erf-GELU score: returns per-quad h2 partial ----------------
// sh.x = sum over j={quad*4+0,+1}, sh.y = sum over j={quad*4+2,+3} of w_j*gelu(x_j).
// gelu = 0.5x(1+E), E(t)=erf(t/sqrt2) ~ t*P(v) deg-3, v=t^2/GCLAMP^2. 0.5*log2e in W.
__device__ __forceinline__ h2 score_sub_h(f32x4 D, h2 WA, h2 WB,
                                          h2 C0, h2 C1, h2 C2, h2 C3,
                                          h2 IVU, h2 LO, h2 HI) {
    h2 sh;
    {
        h2 tr = __builtin_bit_cast(h2, __builtin_amdgcn_cvt_pkrtz(D[0], D[1]));
        h2 t  = __builtin_elementwise_min(__builtin_elementwise_max(tr, LO), HI);
        h2 u = t * t;
        h2 v = u * IVU;
        h2 P = __builtin_elementwise_fma(C3, v, C2);
        P = __builtin_elementwise_fma(P, v, C1);
        P = __builtin_elementwise_fma(P, v, C0);
        h2 E = t * P;
        h2 m = WA * tr;
        sh = __builtin_elementwise_fma(m, E, m);
    }
    {
        h2 tr = __builtin_bit_cast(h2, __builtin_amdgcn_cvt_pkrtz(D[2], D[3]));
        h2 t  = __builtin_elementwise_min(__builtin_elementwise_max(tr, LO), HI);
        h2 u = t * t;
        h2 v = u * IVU;
        h2 P = __builtin_elementwise_fma(C3, v, C2);
        P = __builtin_elementwise_fma(P, v, C1);
        P = __builtin_elementwise_fma(P, v, C0);
        h2 E = t * P;
        h2 m = WB * tr;
        sh = __builtin_elementwise_fma(m, E, sh + m);
    }
    return sh;
}

// ---------------- host: deg-3 LSQ fit of erf(t/sqrt2) ~ t*P(v), v=t^2/umax ----------------
static void fit_gelu_poly(float cf[4]) {
    const int NS = 512;
    const int M = 4;
    const double umax = (double)GCLAMP * (double)GCLAMP;
    double AtA[4][4], Atb[4];
    for (int i = 0; i < M; ++i) { Atb[i] = 0.0; for (int j = 0; j < M; ++j) AtA[i][j] = 0.0; }
    for (int k = 0; k <= NS; ++k) {
        double u = umax * 0.5 * (1.0 - cos(3.14159265358979323846 * (double)k / NS));
        double t = sqrt(u);
        double g = erf(t * 0.7071067811865476);
        double v = u / umax;
        double phi[4];
        double p = t;
        for (int j = 0; j < M; ++j) { phi[j] = p; p *= v; }
        for (int i = 0; i < M; ++i) {
            Atb[i] += phi[i] * g;
            for (int j = 0; j < M; ++j) AtA[i][j] += phi[i] * phi[j];
        }
    }
    for (int col = 0; col < M; ++col) {              // GE w/ partial pivoting
        int piv = col;
        for (int r = col + 1; r < M; ++r)
            if (fabs(AtA[r][col]) > fabs(AtA[piv][col])) piv = r;
        if (piv != col) {
            for (int j = 0; j < M; ++j) { double tm = AtA[col][j]; AtA[col][j] = AtA[piv][j]; AtA[piv][j] = tm; }
            double tb = Atb[col]; Atb[col] = Atb[piv]; Atb[piv] = tb;
        }
        double d = AtA[col][col];
        for (int r = col + 1; r < M; ++r) {
            double f = AtA[r][col] / d;
            for (int j = col; j < M; ++j) AtA[r][j] -= f * AtA[col][j];
            Atb[r] -= f * Atb[col];
        }
    }
    double c[4];
    for (int i = M - 1; i >= 0; --i) {
        double s = Atb[i];
        for (int j = i + 1; j < M; ++j) s -= AtA[i][j] * c[j];
        c[i] = s / AtA[i][i];
    }
    for (int j = 0; j < M; ++j) cf[j] = (float)c[j];  // v-basis, O(0.05..0.8): fp16-safe
}

// ---------------- binding encoder ----------------
__global__ __launch_bounds__(256) void k_binding(const float* __restrict__ x,
                                                 const float* __restrict__ role,
                                                 const float* __restrict__ fw,
                                                 float* __restrict__ h) {
    int idx = blockIdx.x * 256 + threadIdx.x;        // B*C*D = 1048576
    int d  = idx & 63;
    int bc = idx >> 6;
    float xl = log1pf(fmaxf(x[bc], 0.0f));
    float f  = gelu_f(xl * fw[d]);
    h[idx] = role[(bc & (CC - 1)) * DD + d] * f;
}

// ---------------- QKV projection + Aq (=qp+b1) precompute ----------------
__global__ __launch_bounds__(256) void k_qkv(const float* __restrict__ h,
                                             const float* __restrict__ qw, const float* __restrict__ qb,
                                             const float* __restrict__ kw, const float* __restrict__ kb,
                                             const float* __restrict__ vw, const float* __restrict__ vb,
                                             const float* __restrict__ w1, const float* __restrict__ b1,
                                             float* __restrict__ Q, float* __restrict__ K,
                                             float* __restrict__ V, float* __restrict__ A) {
    __shared__ __attribute__((aligned(16))) float hrow[4][64];
    __shared__ float qrow[4][64];
    int r  = threadIdx.x >> 6;
    int j  = threadIdx.x & 63;
    int bc = blockIdx.x * 4 + r;                     // 0..16383
    hrow[r][j] = h[(size_t)bc * 64 + j];
    __syncthreads();
    float aq = qb[j], ak = kb[j], av = vb[j];
    const float4* hr4 = (const float4*)hrow[r];
    const float4* qw4 = (const float4*)(qw + j * 64);
    const float4* kw4 = (const float4*)(kw + j * 64);
    const float4* vw4 = (const float4*)(vw + j * 64);
    #pragma unroll
    for (int i = 0; i < 16; ++i) {
        float4 hv = hr4[i];
        float4 a = qw4[i], b = kw4[i], c = vw4[i];
        aq = fmaf(hv.x, a.x, fmaf(hv.y, a.y, fmaf(hv.z, a.z, fmaf(hv.w, a.w, aq))));
        ak = fmaf(hv.x, b.x, fmaf(hv.y, b.y, fmaf(hv.z, b.z, fmaf(hv.w, b.w, ak))));
        av = fmaf(hv.x, c.x, fmaf(hv.y, c.y, fmaf(hv.z, c.z, fmaf(hv.w, c.w, av))));
    }
    int head = j >> 4, dh = j & 15;
    int b = bc >> 11, c = bc & (CC - 1);
    size_t o = ((size_t)(b * HH + head) * CC + c) * DHH + dh;
    Q[o] = aq; K[o] = ak; V[o] = av;
    qrow[r][j] = aq;
    __syncthreads();
    float aA = b1[dh];
    #pragma unroll
    for (int i = 0; i < 16; ++i)
        aA = fmaf(qrow[r][head * 16 + i], w1[dh * 48 + i], aA);
    A[o] = aA;
}

// ---------------- MFMA attention (64-key tiles, packed-h2 quad reduce, deg-3 gelu) ----------------
// grid: qt(128, 16 queries each) x bh(32) = 4096 blocks, 4 waves/block, 4 q/wave.
__global__ __launch_bounds__(256, 6) void k_attn(const float* __restrict__ Q, const float* __restrict__ K,
                                                 const float* __restrict__ V, const float* __restrict__ A,
                                                 const float* __restrict__ w1g, const float* __restrict__ w2g,
                                                 float* __restrict__ AT,
                                                 float c0, float c1, float c2, float c3) {
    __shared__ __attribute__((aligned(16))) _Float16 Kl[64 * KPAD];   // [key][i0..15,16=1,17..=0]
    __shared__ __attribute__((aligned(16))) _Float16 Vt[16 * VPAD];   // [d][key 0..63]
    __shared__ __attribute__((aligned(16))) _Float16 El[4][16 * KPAD];// per wave [q][key-in-half]

    int tid  = threadIdx.x;
    int lane = tid & 63;
    int w    = tid >> 6;
    int quad = lane >> 4;
    int l15  = lane & 15;
    int qt = blockIdx.x & 127;
    int bh = blockIdx.x >> 7;
    size_t base = (size_t)bh * (CC * DHH);
    int qbase = qt * 16 + w * 4;

    // one-time: Kl const region ([16]=1, rest 0) for 64 rows + zero ALL of El
    for (int idx = tid; idx < 64 * 24; idx += 256) {
        int row = idx / 24, off = 16 + idx % 24;
        Kl[row * KPAD + off] = (off == 16) ? (_Float16)1.0f : (_Float16)0.0f;
    }
    {
        _Float16* Elf = &El[0][0];
        for (int idx = tid; idx < 4 * 16 * KPAD; idx += 256) Elf[idx] = (_Float16)0.0f;
    }

    // gelu poly constants (half2)
    h2 C0 = {(_Float16)c0, (_Float16)c0};
    h2 C1 = {(_Float16)c1, (_Float16)c1};
    h2 C2 = {(_Float16)c2, (_Float16)c2};
    h2 C3 = {(_Float16)c3, (_Float16)c3};
    const float ivu_f = 1.0f / (GCLAMP * GCLAMP);
    h2 IVU = {(_Float16)ivu_f, (_Float16)ivu_f};
    h2 LO = {(_Float16)(-GCLAMP), (_Float16)(-GCLAMP)};
    h2 HI = {(_Float16)GCLAMP, (_Float16)GCLAMP};

    // per-lane w2 pairs for rows j = quad*4+{0..3}; fold 1/sqrt(16)*log2(e)*0.5
    const float wscale = 0.25f * 1.44269504f * 0.5f;
    h2 WA = {(_Float16)(w2g[quad * 4 + 0] * wscale), (_Float16)(w2g[quad * 4 + 1] * wscale)};
    h2 WB = {(_Float16)(w2g[quad * 4 + 2] * wscale), (_Float16)(w2g[quad * 4 + 3] * wscale)};

    bool sel_hi = (lane & 16) != 0;                  // quads 1,3 -> sub1 value at store

    // Bq A-frags: m=j=lane&15, kdim=i=quad*8+jj. quads0,1: W1qk[j][i]*q[i]+W1k[j][i];
    // quad2 jj=0: Aq[j]; else 0. 4 frags (16 regs) live across the K loop.
    half8 bq[4];
    {
        int j = l15;
        #pragma unroll
        for (int q = 0; q < 4; ++q) {
            const float* qv = Q + base + (size_t)(qbase + q) * 16;
            float aqv = A[base + (size_t)(qbase + q) * 16 + j];
            half8 v;
            #pragma unroll
            for (int jj = 0; jj < 8; ++jj) {
                float val;
                if (quad < 2) {
                    int i = quad * 8 + jj;
                    val = fmaf(w1g[j * 48 + 32 + i], qv[i], w1g[j * 48 + 16 + i]);
                } else if (quad == 2 && jj == 0) {
                    val = aqv;
                } else {
                    val = 0.0f;
                }
                v[jj] = (_Float16)val;
            }
            bq[q] = v;
        }
    }

    half8 ones;
    #pragma unroll
    for (int jj = 0; jj < 8; ++jj) ones[jj] = (_Float16)1.0f;
    f32x4 Oc = {0.f, 0.f, 0.f, 0.f};
    f32x4 Dn = {0.f, 0.f, 0.f, 0.f};
    f32x4 zc = {0.f, 0.f, 0.f, 0.f};

    _Float16* Ew = El[w];

    // staging index map: both K and V are one float4 per thread per 64-key tile
    int skey = tid >> 2, sip = (tid & 3) * 4;        // K: (key 0..63, elem 0/4/8/12)
    int vkey = tid >> 2, vd  = (tid & 3) * 4;        // V: (key 0..63, d 0/4/8/12)

    #pragma unroll 1
    for (int t0 = 0; t0 < CC; t0 += 64) {
        __syncthreads();                              // prior tile's LDS readers done
        {   // stage 64 keys of K and V (transposed) with coalesced float4 loads
            float4 kv = *(const float4*)(K + base + (size_t)(t0 + skey) * 16 + sip);
            Kl[skey * KPAD + sip + 0] = (_Float16)kv.x;
            Kl[skey * KPAD + sip + 1] = (_Float16)kv.y;
            Kl[skey * KPAD + sip + 2] = (_Float16)kv.z;
            Kl[skey * KPAD + sip + 3] = (_Float16)kv.w;
            float4 vv = *(const float4*)(V + base + (size_t)(t0 + vkey) * 16 + vd);
            Vt[(vd + 0) * VPAD + vkey] = (_Float16)vv.x;
            Vt[(vd + 1) * VPAD + vkey] = (_Float16)vv.y;
            Vt[(vd + 2) * VPAD + vkey] = (_Float16)vv.z;
            Vt[(vd + 3) * VPAD + vkey] = (_Float16)vv.w;
        }
        __syncthreads();                              // staging visible to all waves

        #pragma unroll
        for (int hf = 0; hf < 2; ++hf) {              // two 32-key halves, no barrier between
            half8 bK0 = *(const half8*)&Kl[(hf * 32 + l15) * KPAD + quad * 8];
            half8 bK1 = *(const half8*)&Kl[(hf * 32 + 16 + l15) * KPAD + quad * 8];

            #pragma unroll
            for (int q = 0; q < 4; ++q) {
                h2 sh0, sh1;
                {
                    f32x4 D0 = __builtin_amdgcn_mfma_f32_16x16x32_f16(bq[q], bK0, zc, 0, 0, 0);
                    sh0 = score_sub_h(D0, WA, WB, C0, C1, C2, C3, IVU, LO, HI);
                }
                {
                    f32x4 D1 = __builtin_amdgcn_mfma_f32_16x16x32_f16(bq[q], bK1, zc, 0, 0, 0);
                    sh1 = score_sub_h(D1, WA, WB, C0, C1, C2, C3, IVU, LO, HI);
                }
                // sp = {sum(sh0), sum(sh1)} then packed quad-reduce (2 shfls, 2 pk-adds)
                h2 tlo = {sh0.x, sh1.x};
                h2 thi = {sh0.y, sh1.y};
                h2 sp = tlo + thi;
                int spi = __builtin_bit_cast(int, sp);
                sp = sp + __builtin_bit_cast(h2, __shfl_xor(spi, 16, 64));
                spi = __builtin_bit_cast(int, sp);
                sp = sp + __builtin_bit_cast(h2, __shfl_xor(spi, 32, 64));
                float uu = sel_hi ? (float)sp.y : (float)sp.x;
                float e = EXP2F(uu);                  // base-2 softmax (log2e folded in W)
                if (lane < 32) Ew[q * KPAD + lane] = (_Float16)e;
            }
            // E·V numerator + E·ones denominator (El rows 4..15 zero -> inert)
            half8 aE = *(const half8*)&Ew[l15 * KPAD + quad * 8];
            half8 bV = *(const half8*)&Vt[l15 * VPAD + hf * 32 + quad * 8];
            Oc = __builtin_amdgcn_mfma_f32_16x16x32_f16(aE, bV, Oc, 0, 0, 0);
            Dn = __builtin_amdgcn_mfma_f32_16x16x32_f16(aE, ones, Dn, 0, 0, 0);
        }
    }

    // D layout: row(q)=quad*4+r, col(d)=lane&15; only rows 0..3 (quad==0) are real q's
    int b = bh >> 2, hh = bh & 3;
    if (quad == 0) {
        #pragma unroll
        for (int r = 0; r < 4; ++r) {
            int c = qbase + r;
            AT[((size_t)(b * CC + c)) * DD + hh * 16 + l15] = Oc[r] / Dn[r];
        }
    }
}

// ---------------- fused post-attention: oproj + LN1 + FFN + LN2 (4 rows/block) ----------------
__global__ __launch_bounds__(256) void k_post(const float* __restrict__ AT,
                                              const float* __restrict__ ow, const float* __restrict__ ob,
                                              const float* __restrict__ g1, const float* __restrict__ be1,
                                              const float* __restrict__ f1w, const float* __restrict__ f1b,
                                              const float* __restrict__ f2w, const float* __restrict__ f2b,
                                              const float* __restrict__ g2, const float* __restrict__ be2,
                                              float* __restrict__ h) {
    int bc0 = blockIdx.x * 4;
    int t  = threadIdx.x;
    int j = t & 63, wv = t >> 6;
    __shared__ __attribute__((aligned(16))) float ar[4][64];
    __shared__ __attribute__((aligned(16))) float hln[4][64];
    __shared__ __attribute__((aligned(16))) float u[4][256];
    __shared__ float parts[4][4][64];                // [row][chunk][j]
    ar[wv][j] = AT[(size_t)(bc0 + wv) * 64 + j];
    __syncthreads();
    {   // out-proj partials: thread (wv=chunk, j=out) for all 4 rows
        float p0 = 0.f, p1 = 0.f, p2 = 0.f, p3 = 0.f;
        const float4* w4 = (const float4*)(ow + j * 64 + wv * 16);
        const float4* a0 = (const float4*)(ar[0] + wv * 16);
        const float4* a1 = (const float4*)(ar[1] + wv * 16);
        const float4* a2 = (const float4*)(ar[2] + wv * 16);
        const float4* a3 = (const float4*)(ar[3] + wv * 16);
        #pragma unroll
        for (int i = 0; i < 4; ++i) {
            float4 wvv = w4[i];
            float4 x0 = a0[i], x1 = a1[i], x2 = a2[i], x3 = a3[i];
            p0 = fmaf(x0.x, wvv.x, fmaf(x0.y, wvv.y, fmaf(x0.z, wvv.z, fmaf(x0.w, wvv.w, p0))));
            p1 = fmaf(x1.x, wvv.x, fmaf(x1.y, wvv.y, fmaf(x1.z, wvv.z, fmaf(x1.w, wvv.w, p1))));
            p2 = fmaf(x2.x, wvv.x, fmaf(x2.y, wvv.y, fmaf(x2.z, wvv.z, fmaf(x2.w, wvv.w, p2))));
            p3 = fmaf(x3.x, wvv.x, fmaf(x3.y, wvv.y, fmaf(x3.z, wvv.z, fmaf(x3.w, wvv.w, p3))));
        }
        parts[0][wv][j] = p0; parts[1][wv][j] = p1; parts[2][wv][j] = p2; parts[3][wv][j] = p3;
    }
    __syncthreads();
    {   // LN1: wave wv handles row wv
        float o = ob[j] + parts[wv][0][j] + parts[wv][1][j] + parts[wv][2][j] + parts[wv][3][j];
        float x = h[(size_t)(bc0 + wv) * 64 + j] + o;
        float m  = wave_sum64(x) * (1.0f / 64.0f);
        float dv = x - m;
        float vv = wave_sum64(dv * dv) * (1.0f / 64.0f);
        float r  = __builtin_amdgcn_rsqf(vv + 1e-5f);
        hln[wv][j] = fmaf(dv * r, g1[j], be1[j]);
    }
    __syncthreads();
    {   // FFN1: thread t computes hidden unit t for all 4 rows (weights loaded once)
        float b = f1b[t];
        float a0 = b, a1 = b, a2 = b, a3 = b;
        const float4* w4 = (const float4*)(f1w + t * 64);
        const float4* h0 = (const float4*)hln[0];
        const float4* h1 = (const float4*)hln[1];
        const float4* h2p = (const float4*)hln[2];
        const float4* h3 = (const float4*)hln[3];
        #pragma unroll
        for (int i = 0; i < 16; ++i) {
            float4 wvv = w4[i];
            float4 x0 = h0[i], x1 = h1[i], x2 = h2p[i], x3 = h3[i];
            a0 = fmaf(x0.x, wvv.x, fmaf(x0.y, wvv.y, fmaf(x0.z, wvv.z, fmaf(x0.w, wvv.w, a0))));
            a1 = fmaf(x1.x, wvv.x, fmaf(x1.y, wvv.y, fmaf(x1.z, wvv.z, fmaf(x1.w, wvv.w, a1))));
            a2 = fmaf(x2.x, wvv.x, fmaf(x2.y, wvv.y, fmaf(x2.z, wvv.z, fmaf(x2.w, wvv.w, a2))));
            a3 = fmaf(x3.x, wvv.x, fmaf(x3.y, wvv.y, fmaf(x3.z, wvv.z, fmaf(x3.w, wvv.w, a3))));
        }
        u[0][t] = gelu_f(a0); u[1][t] = gelu_f(a1); u[2][t] = gelu_f(a2); u[3][t] = gelu_f(a3);
    }
    __syncthreads();
    {   // FFN2 partials
        float p0 = 0.f, p1 = 0.f, p2 = 0.f, p3 = 0.f;
        const float4* w4 = (const float4*)(f2w + j * 256 + wv * 64);
        const float4* u0 = (const float4*)(u[0] + wv * 64);
        const float4* u1 = (const float4*)(u[1] + wv * 64);
        const float4* u2 = (const float4*)(u[2] + wv * 64);
        const float4* u3 = (const float4*)(u[3] + wv * 64);
        #pragma unroll
        for (int i = 0; i < 16; ++i) {
            float4 wvv = w4[i];
            float4 x0 = u0[i], x1 = u1[i], x2 = u2[i], x3 = u3[i];
            p0 = fmaf(x0.x, wvv.x, fmaf(x0.y, wvv.y, fmaf(x0.z, wvv.z, fmaf(x0.w, wvv.w, p0))));
            p1 = fmaf(x1.x, wvv.x, fmaf(x1.y, wvv.y, fmaf(x1.z, wvv.z, fmaf(x1.w, wvv.w, p1))));
            p2 = fmaf(x2.x, wvv.x, fmaf(x2.y, wvv.y, fmaf(x2.z, wvv.z, fmaf(x2.w, wvv.w, p2))));
            p3 = fmaf(x3.x, wvv.x, fmaf(x3.y, wvv.y, fmaf(x3.z, wvv.z, fmaf(x3.w, wvv.w, p3))));
        }
        parts[0][wv][j] = p0; parts[1][wv][j] = p1; parts[2][wv][j] = p2; parts[3][wv][j] = p3;
    }
    __syncthreads();
    {   // LN2: wave wv handles row wv
        float o = f2b[j] + parts[wv][0][j] + parts[wv][1][j] + parts[wv][2][j] + parts[wv][3][j];
        float x = hln[wv][j] + o;
        float m  = wave_sum64(x) * (1.0f / 64.0f);
        float dv = x - m;
        float vv = wave_sum64(dv * dv) * (1.0f / 64.0f);
        float r  = __builtin_amdgcn_rsqf(vv + 1e-5f);
        h[(size_t)(bc0 + wv) * 64 + j] = fmaf(dv * r, g2[j], be2[j]);
    }
}

// ---------------- task-query readout ----------------
__global__ __launch_bounds__(256) void k_readout(const float* __restrict__ h,
                                                 const float* __restrict__ tq,
                                                 const float* __restrict__ hw, const float* __restrict__ hb,
                                                 float* __restrict__ out) {
    int b = blockIdx.x;
    int t = threadIdx.x;
    __shared__ float ebuf[2048];
    __shared__ float tqs[64];
    __shared__ float sred[256];
    __shared__ float red[4][64];
    if (t < 64) tqs[t] = tq[t];
    __syncthreads();
    float ss = 0.0f;
    for (int c = t; c < CC; c += 256) {
        const float* hrow = h + ((size_t)b * CC + c) * 64;
        float s = 0.0f;
        #pragma unroll
        for (int d = 0; d < 64; ++d) s = fmaf(hrow[d], tqs[d], s);
        float e = __expf(s * 0.125f);                 // scores ~ +-0.1: max-free safe
        ebuf[c] = e; ss += e;
    }
    sred[t] = ss;
    __syncthreads();
    for (int o = 128; o; o >>= 1) {
        if (t < o) sred[t] += sred[t + o];
        __syncthreads();
    }
    float inv = 1.0f / sred[0];
    int d = t & 63, ch = t >> 6;
    float p = 0.0f;
    for (int c = ch * 512; c < ch * 512 + 512; ++c)
        p = fmaf(ebuf[c], h[((size_t)b * CC + c) * 64 + d], p);
    red[ch][d] = p;
    __syncthreads();
    if (t < 64) red[0][t] = (red[0][t] + red[1][t] + red[2][t] + red[3][t]) * inv;
    __syncthreads();
    if (t < 10) {
        float o = hb[t];
        #pragma unroll
        for (int d2 = 0; d2 < 64; ++d2) o = fmaf(red[0][d2], hw[t * 64 + d2], o);
        out[b * 10 + t] = o;
    }
}

extern "C" void kernel_launch(void* const* d_in, const int* in_sizes, int n_in,
                              void* d_out, int out_size, void* d_ws, size_t ws_size,
                              hipStream_t stream) {
    (void)in_sizes; (void)n_in; (void)out_size; (void)ws_size;
    const float* x    = (const float*)d_in[0];
    const float* role = (const float*)d_in[1];
    const float* fw   = (const float*)d_in[2];
    const float* qw   = (const float*)d_in[3];
    const float* qb   = (const float*)d_in[4];
    const float* kw   = (const float*)d_in[5];
    const float* kb   = (const float*)d_in[6];
    const float* vw   = (const float*)d_in[7];
    const float* vb   = (const float*)d_in[8];
    const float* w1   = (const float*)d_in[9];
    const float* b1   = (const float*)d_in[10];
    const float* w2   = (const float*)d_in[11];
    // d_in[12] = b2: softmax-shift-invariant, dropped
    const float* ow   = (const float*)d_in[13];
    const float* ob   = (const float*)d_in[14];
    const float* g1   = (const float*)d_in[15];
    const float* be1  = (const float*)d_in[16];
    const float* f1w  = (const float*)d_in[17];
    const float* f1b  = (const float*)d_in[18];
    const float* f2w  = (const float*)d_in[19];
    const float* f2b  = (const float*)d_in[20];
    const float* g2   = (const float*)d_in[21];
    const float* be2  = (const float*)d_in[22];
    const float* tq   = (const float*)d_in[23];
    const float* hw   = (const float*)d_in[24];
    const float* hb   = (const float*)d_in[25];

    float cf[4];
    fit_gelu_poly(cf);                               // deterministic per call (~us, host-only)

    float* ws   = (float*)d_ws;
    const size_t M = 1048576;                        // B*C*D
    float* H    = ws;
    float* Q    = ws + 1 * M;
    float* K    = ws + 2 * M;
    float* V    = ws + 3 * M;
    float* Abuf = ws + 4 * M;
    float* AT   = ws + 5 * M;

    k_binding<<<4096, 256, 0, stream>>>(x, role, fw, H);
    for (int l = 0; l < LL; ++l) {
        k_qkv<<<4096, 256, 0, stream>>>(H, qw + l * 4096, qb + l * 64, kw + l * 4096, kb + l * 64,
                                        vw + l * 4096, vb + l * 64, w1 + l * 768, b1 + l * 16,
                                        Q, K, V, Abuf);
        k_attn<<<4096, 256, 0, stream>>>(Q, K, V, Abuf, w1 + l * 768, w2 + l * 16, AT,
                                         cf[0], cf[1], cf[2], cf[3]);
        k_post<<<4096, 256, 0, stream>>>(AT, ow + l * 4096, ob + l * 64, g1 + l * 64, be1 + l * 64,
                                         f1w + l * 16384, f1b + l * 256, f2w + l * 16384,
                                         f2b + l * 64, g2 + l * 64, be2 + l * 64, H);
    }
    k_readout<<<8, 256, 0, stream>>>(H, tq, hw, hb, (float*)d_out);
}